// Round 1
// baseline (1184.696 us; speedup 1.0000x reference)
//
#include <hip/hip_runtime.h>

// DecoderWithAttention: B=16, T=32, F=8, S_ENC=256, H=512, L=2.
// R6 = R5 skeleton (2 halves x 128 row-slice blocks, 256 thr) minus stage C:
//  - Stage B atomicAdds unnormalized weighted partials + L into per-parity fp32
//    accumulators at the coherence point; stage D normalizes on load.
//    (kills 1 of 5 barriers/step and the 512KB/step wpart HBM round trip)
//  - GRU layer-0 weights + whid + biases + own outW cols pinned in LDS (~30KB;
//    total static LDS 59.8KB). Layer-1 weights stay L2-resident (cached loads).
//  - Prologue uses plain cached stores + ONE agent release fence per block at
//    the grid barrier (single wbl2/inv per block, once per launch).
//  - out base term (wei+xin+bias) computed in stage D by sgrp==14 block;
//    finalize (sum 128 outP partials + relu) in stage A of t+1 by sgrp==15.
// R7: identical schedule; removed dead no-op guard in stage D (re-baseline
//     after infra bench failure).

namespace {
constexpr int kB = 16, kT = 32, kF = 8, kS = 256, kH = 512;
constexpr int NBLK = 256, NTHR = 256;

// ws float offsets. [0..63]: barrier counters (half0@0, half1@32, grid@64).
constexpr int OFF_AEH   = 1024;                   // [512][256] u32 attn_W[:,512:]
constexpr int OFF_WHID  = OFF_AEH + 131072;       // [512][256] u32 attn_W[:,:512]
constexpr int OFF_WIH0  = OFF_WHID + 131072;      // [1536][260] u32
constexpr int OFF_WHH0  = OFF_WIH0 + 399360;      // [1536][256] u32
constexpr int OFF_WIH1  = OFF_WHH0 + 393216;      // [1536][256] u32
constexpr int OFF_WHH1  = OFF_WIH1 + 393216;      // [1536][256] u32
constexpr int OFF_ENCH  = OFF_WHH1 + 393216;      // [4096][256] u32 enc f16
constexpr int OFF_ENCP  = OFF_ENCH + 1048576;     // [4096][256] u32 enc_proj f16
constexpr int OFF_HIDP  = OFF_ENCP + 1048576;     // [16][512] f32
constexpr int OFF_WEIA  = OFF_HIDP + 8192;        // [2][16][512] f32 accumulators
constexpr int OFF_LACC  = OFF_WEIA + 16384;       // [2][16] f32 accumulators
constexpr int OFF_OUTB  = OFF_LACC + 32;          // [2][16][8] f32
constexpr int OFF_H0C   = OFF_OUTB + 256;         // [2][16][256] u32
constexpr int OFF_H1C   = OFF_H0C + 8192;         // [2][16][256] u32
constexpr int OFF_XINC  = OFF_H1C + 8192;         // [2][16][8] f32
constexpr int OFF_OUTP  = OFF_XINC + 256;         // [16][128][8] f32

// LDS float/u32 offsets (shared indexing; total 14960 floats = 59.8 KB)
constexpr int L_WIH0 = 0;        // [12][264] u32 (260 + 4 zero pad)
constexpr int L_WHH0 = 3168;     // [12][256] u32
constexpr int L_WHID = 6240;     // [4][256] u32
constexpr int L_BIH0 = 7264, L_BHH0 = 7276, L_BIH1 = 7288, L_BHH1 = 7300;
constexpr int L_OOW  = 7312;     // [8][4] f32 outW own cols
constexpr int L_VW   = 7344;     // [512] f32
constexpr int L_H1   = 7856;     // [8][264] u32 (persists A->E)
constexpr int L_HX   = 9968;     // [8][264] u32
constexpr int L_H0   = 12080;    // [8][264] u32
constexpr int L_HIDP = 14192;    // [512] f32
constexpr int L_ES   = 14704;    // [16]
constexpr int L_AX   = 14720;    // [96]
constexpr int L_AH   = 14816;    // [96]
constexpr int L_HS   = 14912;    // [32]
constexpr int L_XINL = 14944;    // [8]
constexpr int L_INV  = 14952;    // [8]
constexpr int LDS_FLOATS = 14960;
}  // namespace

typedef _Float16 h2 __attribute__((ext_vector_type(2)));
union U32H { unsigned u; h2 h; };

__device__ __forceinline__ float dot2(unsigned a, unsigned b, float acc) {
    U32H ua, ub; ua.u = a; ub.u = b;
#if __has_builtin(__builtin_amdgcn_fdot2)
    return __builtin_amdgcn_fdot2(ua.h, ub.h, acc, false);
#else
    return acc + (float)ua.h.x * (float)ub.h.x + (float)ua.h.y * (float)ub.h.y;
#endif
}
__device__ __forceinline__ unsigned packh2(float a, float b) {
    U32H u; u.h = h2{(_Float16)a, (_Float16)b}; return u.u;
}
__device__ __forceinline__ float fsig(float x) { return 1.0f / (1.0f + __expf(-x)); }
__device__ __forceinline__ float ftanhf(float x) {
    float e = __expf(2.0f * x);
    return 1.0f - 2.0f / (e + 1.0f);
}
// Uncached per-access comm ops (sc0 sc1 -> coherence point).
__device__ __forceinline__ float cload(const float* p) {
    return __hip_atomic_load(p, __ATOMIC_RELAXED, __HIP_MEMORY_SCOPE_SYSTEM);
}
__device__ __forceinline__ void cstore(float* p, float v) {
    __hip_atomic_store(p, v, __ATOMIC_RELAXED, __HIP_MEMORY_SCOPE_SYSTEM);
}
__device__ __forceinline__ unsigned ucload(const unsigned* p) {
    return __hip_atomic_load(p, __ATOMIC_RELAXED, __HIP_MEMORY_SCOPE_SYSTEM);
}

// Main-loop barrier (validated R2/R4/R5): no cache maintenance.
__device__ __forceinline__ void bar_sync(unsigned* cnt, unsigned target) {
    __syncthreads();
    if (threadIdx.x == 0) {
        __builtin_amdgcn_fence(__ATOMIC_RELEASE, "workgroup");
        __builtin_amdgcn_s_waitcnt(0);
        __hip_atomic_fetch_add(cnt, 1u, __ATOMIC_RELAXED, __HIP_MEMORY_SCOPE_SYSTEM);
        while (__hip_atomic_load(cnt, __ATOMIC_RELAXED, __HIP_MEMORY_SCOPE_SYSTEM) < target)
            __builtin_amdgcn_s_sleep(1);
        __builtin_amdgcn_fence(__ATOMIC_ACQUIRE, "workgroup");
    }
    __syncthreads();
}

// Prologue barrier: one agent-scope wbl2 (release) / inv (acquire) per block.
__device__ __forceinline__ void bar_sync_flush(unsigned* cnt, unsigned target) {
    __syncthreads();
    if (threadIdx.x == 0) {
        __builtin_amdgcn_fence(__ATOMIC_RELEASE, "agent");
        __hip_atomic_fetch_add(cnt, 1u, __ATOMIC_RELAXED, __HIP_MEMORY_SCOPE_SYSTEM);
        while (__hip_atomic_load(cnt, __ATOMIC_RELAXED, __HIP_MEMORY_SCOPE_SYSTEM) < target)
            __builtin_amdgcn_s_sleep(8);
        __builtin_amdgcn_fence(__ATOMIC_ACQUIRE, "agent");
    }
    __syncthreads();
}

__global__ __launch_bounds__(NTHR) void decoder_kernel(
    const float* __restrict__ target, const float* __restrict__ hidden0,
    const float* __restrict__ enc, const float* __restrict__ attn_W,
    const float* __restrict__ attn_b, const float* __restrict__ v_w,
    const float* __restrict__ Wih0, const float* __restrict__ Whh0,
    const float* __restrict__ bih0, const float* __restrict__ bhh0,
    const float* __restrict__ Wih1, const float* __restrict__ Whh1,
    const float* __restrict__ bih1, const float* __restrict__ bhh1,
    const float* __restrict__ outW, const float* __restrict__ outBias,
    float* __restrict__ out, float* __restrict__ ws) {
    const int tid = threadIdx.x, bid = blockIdx.x;
    const int half = bid >> 7, j = bid & 127;
    const int bloc = j >> 4, sgrp = j & 15;
    const int b_att = half * 8 + bloc;
    unsigned* halfCnt = (unsigned*)ws + 32 * half;
    unsigned* gridCnt = (unsigned*)ws + 64;
    unsigned bars = 0;

    unsigned* aehU  = (unsigned*)(ws + OFF_AEH);
    unsigned* whidU = (unsigned*)(ws + OFF_WHID);
    unsigned* wih0U = (unsigned*)(ws + OFF_WIH0);
    unsigned* whh0U = (unsigned*)(ws + OFF_WHH0);
    unsigned* wih1U = (unsigned*)(ws + OFF_WIH1);
    unsigned* whh1U = (unsigned*)(ws + OFF_WHH1);
    unsigned* encU  = (unsigned*)(ws + OFF_ENCH);
    unsigned* encpU = (unsigned*)(ws + OFF_ENCP);
    float* hidP  = ws + OFF_HIDP;
    float* weiA  = ws + OFF_WEIA;
    float* lacc  = ws + OFF_LACC;
    float* outBs = ws + OFF_OUTB;
    unsigned* h0cU = (unsigned*)(ws + OFF_H0C);
    unsigned* h1cU = (unsigned*)(ws + OFF_H1C);
    float* xinC = ws + OFF_XINC;
    float* outP = ws + OFF_OUTP;

    __shared__ __align__(16) float lds[LDS_FLOATS];
    unsigned* ldsU = (unsigned*)lds;
    const int gtid = bid * NTHR + tid;

    // ===================== P1: f16 pack + state + accumulator init (plain) ====
    for (int i = gtid; i < 131072; i += NBLK * NTHR) {
        const int jr = i >> 8, p = i & 255;
        aehU[i]  = packh2(attn_W[jr * 1024 + 512 + 2 * p], attn_W[jr * 1024 + 513 + 2 * p]);
        whidU[i] = packh2(attn_W[jr * 1024 + 2 * p], attn_W[jr * 1024 + 1 + 2 * p]);
    }
    for (int i = gtid; i < 399360; i += NBLK * NTHR)
        wih0U[i] = packh2(Wih0[2 * i], Wih0[2 * i + 1]);
    for (int i = gtid; i < 393216; i += NBLK * NTHR) {
        whh0U[i] = packh2(Whh0[2 * i], Whh0[2 * i + 1]);
        wih1U[i] = packh2(Wih1[2 * i], Wih1[2 * i + 1]);
        whh1U[i] = packh2(Whh1[2 * i], Whh1[2 * i + 1]);
    }
    for (int i = gtid; i < 1048576; i += NBLK * NTHR)
        encU[i] = packh2(enc[2 * i], enc[2 * i + 1]);
    if (gtid < 4096) {
        const int bb = gtid >> 8, p = gtid & 255;
        h0cU[gtid] = packh2(hidden0[bb * 512 + 2 * p], hidden0[bb * 512 + 2 * p + 1]);
        h1cU[gtid] = packh2(hidden0[8192 + bb * 512 + 2 * p], hidden0[8192 + bb * 512 + 2 * p + 1]);
    }
    if (gtid < 128) {
        const int bb = gtid >> 3, f = gtid & 7;
        xinC[gtid] = target[bb * 256 + f];
    }
    for (int i = gtid; i < 16672; i += NBLK * NTHR)  // weiA + lacc + outBs zero
        ws[OFF_WEIA + i] = 0.f;
    bar_sync_flush(gridCnt, NBLK);  // one wbl2/inv per block

    // ===================== P2: enc_proj for own (b_att, 16 s) =================
    {
        for (int i = 0; i < 16; ++i) {
            const int idx = tid + i * 256;
            const int s = idx >> 8, p = idx & 255;
            ldsU[idx] = encU[(b_att * 256 + sgrp * 16 + s) * 256 + p];
        }
        __syncthreads();
        float a0[16], a1[16];
        const float bb0 = attn_b[2 * tid], bb1 = attn_b[2 * tid + 1];
#pragma unroll
        for (int s = 0; s < 16; ++s) { a0[s] = bb0; a1[s] = bb1; }
        const unsigned* w0 = &aehU[(2 * tid) * 256];
        const unsigned* w1 = &aehU[(2 * tid + 1) * 256];
        for (int p = 0; p < 256; ++p) {
            const unsigned ww0 = w0[p], ww1 = w1[p];
#pragma unroll
            for (int s = 0; s < 16; ++s) {
                const unsigned e = ldsU[s * 256 + p];
                a0[s] = dot2(e, ww0, a0[s]);
                a1[s] = dot2(e, ww1, a1[s]);
            }
        }
        for (int s = 0; s < 16; ++s)  // self-read only
            encpU[(b_att * 256 + sgrp * 16 + s) * 256 + tid] = packh2(a0[s], a1[s]);
        __syncthreads();
    }

    // ===================== P3: pin layer-0 weights + whid + misc in LDS =======
    for (int gh = 0; gh < 12; ++gh) {
        const int grow = (gh >> 2) * 512 + j * 4 + (gh & 3);
        for (int p = tid; p < 260; p += 256) ldsU[L_WIH0 + gh * 264 + p] = wih0U[grow * 260 + p];
        if (tid < 4) ldsU[L_WIH0 + gh * 264 + 260 + tid] = 0u;
        ldsU[L_WHH0 + gh * 256 + tid] = whh0U[grow * 256 + tid];
    }
    for (int r = 0; r < 4; ++r) ldsU[L_WHID + r * 256 + tid] = whidU[(j * 4 + r) * 256 + tid];
    if (tid < 12) {
        const int grow = (tid >> 2) * 512 + j * 4 + (tid & 3);
        lds[L_BIH0 + tid] = bih0[grow]; lds[L_BHH0 + tid] = bhh0[grow];
        lds[L_BIH1 + tid] = bih1[grow]; lds[L_BHH1 + tid] = bhh1[grow];
    }
    if (tid < 32) lds[L_OOW + tid] = outW[(tid >> 2) * 1032 + j * 4 + (tid & 3)];
    lds[L_VW + tid] = v_w[tid];
    lds[L_VW + 256 + tid] = v_w[256 + tid];
    __syncthreads();

    // ===================== main recurrence: A | B | D | E =====================
    for (int t = 0; t < kT; ++t) {
        const int par = t & 1;

        // ---- A: finalize out[t-1] + stage h1 + hidp rows ----
        if (t > 0 && sgrp == 15 && tid < 64) {
            const int f = tid >> 3, sub = tid & 7;
            float acc = 0.f;
            for (int i = 0; i < 16; ++i)
                acc += cload(&outP[(b_att * 128 + sub * 16 + i) * 8 + f]);
            acc += __shfl_down(acc, 4, 8); acc += __shfl_down(acc, 2, 8); acc += __shfl_down(acc, 1, 8);
            if (sub == 0) {
                acc += cload(&outBs[(par ^ 1) * 128 + b_att * 8 + f]);
                const float o = fmaxf(acc, 0.f);
                out[b_att * 256 + (t - 1) * 8 + f] = o;
                cstore(&xinC[par * 128 + b_att * 8 + f], o);
            }
        }
        for (int i = 0; i < 8; ++i) {
            const int idx = tid + i * 256;
            const int bb = idx >> 8, p = idx & 255;
            ldsU[L_H1 + bb * 264 + p] = ucload(&h1cU[par * 4096 + (half * 8 + bb) * 256 + p]);
        }
        __syncthreads();
        {
            const int unit = tid >> 3, sub = tid & 7;
            const int r = unit >> 3, bb = unit & 7;
            const uint4* wrow = (const uint4*)&ldsU[L_WHID + r * 256 + sub * 32];
            const uint4* h1p = (const uint4*)&ldsU[L_H1 + bb * 264 + sub * 32];
            float acc = 0.f;
#pragma unroll
            for (int k4 = 0; k4 < 8; ++k4) {
                const uint4 hv = h1p[k4], wv = wrow[k4];
                acc = dot2(hv.x, wv.x, acc); acc = dot2(hv.y, wv.y, acc);
                acc = dot2(hv.z, wv.z, acc); acc = dot2(hv.w, wv.w, acc);
            }
            acc += __shfl_down(acc, 4, 8); acc += __shfl_down(acc, 2, 8); acc += __shfl_down(acc, 1, 8);
            if (sub == 0) cstore(&hidP[(half * 8 + bb) * 512 + j * 4 + r], acc);
        }
        bar_sync(halfCnt, 128 * (++bars));

        // ---- B: energy (16 s) + exp + atomicAdd weighted/L ----
        lds[L_HIDP + tid] = cload(&hidP[b_att * 512 + tid]);
        lds[L_HIDP + 256 + tid] = cload(&hidP[b_att * 512 + 256 + tid]);
        __syncthreads();
        {
            const int sloc = tid >> 4, sub = tid & 15;
            const unsigned* ep = &encpU[(b_att * 256 + sgrp * 16 + sloc) * 256];
            float acc = 0.f;
#pragma unroll 4
            for (int k2 = 0; k2 < 16; ++k2) {
                const int p = k2 * 16 + sub;
                U32H u; u.u = ep[p];
                acc += lds[L_VW + 2 * p] * ftanhf((float)u.h.x + lds[L_HIDP + 2 * p]);
                acc += lds[L_VW + 2 * p + 1] * ftanhf((float)u.h.y + lds[L_HIDP + 2 * p + 1]);
            }
            acc += __shfl_down(acc, 8, 16); acc += __shfl_down(acc, 4, 16);
            acc += __shfl_down(acc, 2, 16); acc += __shfl_down(acc, 1, 16);
            if (sub == 0) lds[L_ES + sloc] = __expf(acc);  // |score|<=~20: fp32-safe
        }
        __syncthreads();
        {
            float wp0 = 0.f, wp1 = 0.f;
            const unsigned* er = &encU[(b_att * 256 + sgrp * 16) * 256 + tid];
#pragma unroll
            for (int sl = 0; sl < 16; ++sl) {
                U32H u; u.u = er[sl * 256];
                const float es = lds[L_ES + sl];
                wp0 += es * (float)u.h.x; wp1 += es * (float)u.h.y;
            }
            atomicAdd(&weiA[par * 8192 + b_att * 512 + 2 * tid], wp0);
            atomicAdd(&weiA[par * 8192 + b_att * 512 + 2 * tid + 1], wp1);
            if (tid == 0) {
                float l = 0.f;
#pragma unroll
                for (int i = 0; i < 16; ++i) l += lds[L_ES + i];
                atomicAdd(&lacc[par * 16 + b_att], l);
            }
        }
        bar_sync(halfCnt, 128 * (++bars));

        // ---- D: normalize wei + GRU0 rows + out base term ----
        if (tid < 8) {
            const float L = cload(&lacc[par * 16 + half * 8 + tid]);
            lds[L_INV + tid] = 1.f / L;
        }
        if (sgrp == 14 && tid >= 8 && tid < 16)
            lds[L_XINL + tid - 8] = cload(&xinC[par * 128 + b_att * 8 + (tid - 8)]);
        if (tid >= 32 && tid < 64) {
            const int bb = (tid - 32) >> 2, q4 = (tid - 32) & 3;
            const float f0 = cload(&xinC[par * 128 + (half * 8 + bb) * 8 + 2 * q4]);
            const float f1 = cload(&xinC[par * 128 + (half * 8 + bb) * 8 + 2 * q4 + 1]);
            ldsU[L_HX + bb * 264 + q4] = packh2(f0, f1);
            ldsU[L_HX + bb * 264 + 260 + q4] = 0u;  // zero tail pad
        }
        for (int i = 0; i < 8; ++i) {
            const int idx = tid + i * 256;
            const int bb = idx >> 8, p = idx & 255;
            ldsU[L_H0 + bb * 264 + p] = ucload(&h0cU[par * 4096 + (half * 8 + bb) * 256 + p]);
        }
        __syncthreads();
        for (int i = 0; i < 8; ++i) {
            const int idx = tid + i * 256;
            const int bb = idx >> 8, p = idx & 255;
            const float w0 = cload(&weiA[par * 8192 + (half * 8 + bb) * 512 + 2 * p]);
            const float w1 = cload(&weiA[par * 8192 + (half * 8 + bb) * 512 + 2 * p + 1]);
            const float inv = lds[L_INV + bb];
            ldsU[L_HX + bb * 264 + 4 + p] = packh2(w0 * inv, w1 * inv);
        }
        __syncthreads();
        if (tid < 192) {
            const int u = tid >> 1, sub = tid & 1;
            const int bb = u & 7, gh = u >> 3;
            const uint4* wx = (const uint4*)&ldsU[L_WIH0 + gh * 264 + sub * 132];
            const uint4* xp = (const uint4*)&ldsU[L_HX + bb * 264 + sub * 132];
            float ax = 0.f;
#pragma unroll 11
            for (int k4 = 0; k4 < 33; ++k4) {
                const uint4 xv = xp[k4], wv = wx[k4];
                ax = dot2(xv.x, wv.x, ax); ax = dot2(xv.y, wv.y, ax);
                ax = dot2(xv.z, wv.z, ax); ax = dot2(xv.w, wv.w, ax);
            }
            const uint4* wh = (const uint4*)&ldsU[L_WHH0 + gh * 256 + sub * 128];
            const uint4* hp = (const uint4*)&ldsU[L_H0 + bb * 264 + sub * 128];
            float ah = 0.f;
#pragma unroll 8
            for (int k4 = 0; k4 < 32; ++k4) {
                const uint4 hv = hp[k4], wv = wh[k4];
                ah = dot2(hv.x, wv.x, ah); ah = dot2(hv.y, wv.y, ah);
                ah = dot2(hv.z, wv.z, ah); ah = dot2(hv.w, wv.w, ah);
            }
            ax += __shfl_down(ax, 1, 2); ah += __shfl_down(ah, 1, 2);
            if (sub == 0) {
                lds[L_AX + gh * 8 + bb] = ax + lds[L_BIH0 + gh];
                lds[L_AH + gh * 8 + bb] = ah + lds[L_BHH0 + gh];
            }
        }
        __syncthreads();
        if (tid < 32) {
            const int hr = tid >> 3, bb = tid & 7;
            const float r = fsig(lds[L_AX + hr * 8 + bb] + lds[L_AH + hr * 8 + bb]);
            const float z = fsig(lds[L_AX + (4 + hr) * 8 + bb] + lds[L_AH + (4 + hr) * 8 + bb]);
            const float n = ftanhf(lds[L_AX + (8 + hr) * 8 + bb] + r * lds[L_AH + (8 + hr) * 8 + bb]);
            U32H u; u.u = ldsU[L_H0 + bb * 264 + j * 2 + (hr >> 1)];
            const float hold = (hr & 1) ? (float)u.h.y : (float)u.h.x;
            lds[L_HS + hr * 8 + bb] = (1.f - z) * n + z * hold;
        }
        if (sgrp == 14 && tid >= 64 && tid < 128) {
            const int f = (tid - 64) >> 3, sub2 = tid & 7;
            float acc = 0.f;
            const float* ow = &outW[f * 1032 + 512 + sub2 * 64];
#pragma unroll 8
            for (int p2 = 0; p2 < 32; ++p2) {
                U32H u; u.u = ldsU[L_HX + bloc * 264 + 4 + sub2 * 32 + p2];
                acc += ow[2 * p2] * (float)u.h.x + ow[2 * p2 + 1] * (float)u.h.y;
            }
            acc += __shfl_down(acc, 4, 8); acc += __shfl_down(acc, 2, 8); acc += __shfl_down(acc, 1, 8);
            if (sub2 == 0) {
#pragma unroll
                for (int ff = 0; ff < 8; ++ff)
                    acc += outW[f * 1032 + 1024 + ff] * lds[L_XINL + ff];
                cstore(&outBs[par * 128 + b_att * 8 + f], acc + outBias[f]);
            }
        }
        __syncthreads();
        if (tid < 16) {
            const int pp = tid >> 3, bb = tid & 7;
            __hip_atomic_store(&h0cU[(par ^ 1) * 4096 + (half * 8 + bb) * 256 + j * 2 + pp],
                               packh2(lds[L_HS + (2 * pp) * 8 + bb], lds[L_HS + (2 * pp + 1) * 8 + bb]),
                               __ATOMIC_RELAXED, __HIP_MEMORY_SCOPE_SYSTEM);
        }
        bar_sync(halfCnt, 128 * (++bars));

        // ---- E: GRU1 rows + outP partials + accumulator re-zero ----
        for (int i = 0; i < 8; ++i) {
            const int idx = tid + i * 256;
            const int bb = idx >> 8, p = idx & 255;
            ldsU[L_HX + bb * 264 + p] = ucload(&h0cU[(par ^ 1) * 4096 + (half * 8 + bb) * 256 + p]);
        }
        __syncthreads();
        if (tid < 192) {
            const int u = tid >> 1, sub = tid & 1;
            const int bb = u & 7, gh = u >> 3;
            const int grow = (gh >> 2) * 512 + j * 4 + (gh & 3);
            const uint4* wx = (const uint4*)&wih1U[grow * 256 + sub * 128];
            const uint4* xp = (const uint4*)&ldsU[L_HX + bb * 264 + sub * 128];
            float ax = 0.f;
#pragma unroll 8
            for (int k4 = 0; k4 < 32; ++k4) {
                const uint4 xv = xp[k4], wv = wx[k4];
                ax = dot2(xv.x, wv.x, ax); ax = dot2(xv.y, wv.y, ax);
                ax = dot2(xv.z, wv.z, ax); ax = dot2(xv.w, wv.w, ax);
            }
            const uint4* wh = (const uint4*)&whh1U[grow * 256 + sub * 128];
            const uint4* hp = (const uint4*)&ldsU[L_H1 + bb * 264 + sub * 128];
            float ah = 0.f;
#pragma unroll 8
            for (int k4 = 0; k4 < 32; ++k4) {
                const uint4 hv = hp[k4], wv = wh[k4];
                ah = dot2(hv.x, wv.x, ah); ah = dot2(hv.y, wv.y, ah);
                ah = dot2(hv.z, wv.z, ah); ah = dot2(hv.w, wv.w, ah);
            }
            ax += __shfl_down(ax, 1, 2); ah += __shfl_down(ah, 1, 2);
            if (sub == 0) {
                lds[L_AX + gh * 8 + bb] = ax + lds[L_BIH1 + gh];
                lds[L_AH + gh * 8 + bb] = ah + lds[L_BHH1 + gh];
            }
        }
        __syncthreads();
        if (tid < 32) {
            const int hr = tid >> 3, bb = tid & 7;
            const float r = fsig(lds[L_AX + hr * 8 + bb] + lds[L_AH + hr * 8 + bb]);
            const float z = fsig(lds[L_AX + (4 + hr) * 8 + bb] + lds[L_AH + (4 + hr) * 8 + bb]);
            const float n = ftanhf(lds[L_AX + (8 + hr) * 8 + bb] + r * lds[L_AH + (8 + hr) * 8 + bb]);
            U32H u; u.u = ldsU[L_H1 + bb * 264 + j * 2 + (hr >> 1)];
            const float hold = (hr & 1) ? (float)u.h.y : (float)u.h.x;
            lds[L_HS + hr * 8 + bb] = (1.f - z) * n + z * hold;
        }
        __syncthreads();
        if (tid < 16) {
            const int pp = tid >> 3, bb = tid & 7;
            __hip_atomic_store(&h1cU[(par ^ 1) * 4096 + (half * 8 + bb) * 256 + j * 2 + pp],
                               packh2(lds[L_HS + (2 * pp) * 8 + bb], lds[L_HS + (2 * pp + 1) * 8 + bb]),
                               __ATOMIC_RELAXED, __HIP_MEMORY_SCOPE_SYSTEM);
        }
        if (tid < 64) {
            const int f = tid >> 3, bb = tid & 7;
            float acc = 0.f;
#pragma unroll
            for (int hr = 0; hr < 4; ++hr)
                acc += lds[L_OOW + f * 4 + hr] * lds[L_HS + hr * 8 + bb];
            cstore(&outP[((half * 8 + bb) * 128 + j) * 8 + f], acc);
        }
        if (tid < 32) cstore(&weiA[par * 8192 + half * 4096 + j * 32 + tid], 0.f);
        if (sgrp == 0 && tid == 0) cstore(&lacc[par * 16 + b_att], 0.f);
        bar_sync(halfCnt, 128 * (++bars));
    }

    // ---- epilogue: finalize out[31] (par(31) = 1) ----
    if (sgrp == 15 && tid < 64) {
        const int f = tid >> 3, sub = tid & 7;
        float acc = 0.f;
        for (int i = 0; i < 16; ++i)
            acc += cload(&outP[(b_att * 128 + sub * 16 + i) * 8 + f]);
        acc += __shfl_down(acc, 4, 8); acc += __shfl_down(acc, 2, 8); acc += __shfl_down(acc, 1, 8);
        if (sub == 0) {
            acc += cload(&outBs[1 * 128 + b_att * 8 + f]);
            out[b_att * 256 + 31 * 8 + f] = fmaxf(acc, 0.f);
        }
    }
}

extern "C" void kernel_launch(void* const* d_in, const int* in_sizes, int n_in,
                              void* d_out, int out_size, void* d_ws, size_t ws_size,
                              hipStream_t stream) {
    (void)in_sizes; (void)n_in; (void)out_size; (void)ws_size;
    hipMemsetAsync(d_ws, 0, 4096, stream);  // zero barrier counters
    decoder_kernel<<<NBLK, NTHR, 0, stream>>>(
        (const float*)d_in[0], (const float*)d_in[1], (const float*)d_in[2],
        (const float*)d_in[3], (const float*)d_in[4], (const float*)d_in[5],
        (const float*)d_in[6], (const float*)d_in[7], (const float*)d_in[8],
        (const float*)d_in[9], (const float*)d_in[10], (const float*)d_in[11],
        (const float*)d_in[12], (const float*)d_in[13], (const float*)d_in[14],
        (const float*)d_in[15], (float*)d_out, (float*)d_ws);
}

// Round 2
// 1168.939 us; speedup vs baseline: 1.0135x; 1.0135x over previous
//
#include <hip/hip_runtime.h>

// DecoderWithAttention: B=16, T=32, F=8, S_ENC=256, H=512, L=2.
// R8 = R7 skeleton with the sync structure reworked (theory: half-barrier
// arrival is serialized same-address RMW at the coherence point):
//  - Stage A now computes hidP rows [sgrp*32,+32) for OWN b_att only, reading
//    whid rows from L2 (32KB/block/step, shared by 16 blocks -> L2-hit).
//    A->B dependency becomes a 16-block group barrier (1 counter per b_att).
//  - The 3 remaining half-grid barriers use 8 sub-counters (one per bloc,
//    128B apart): arrival serialization 128 -> 16 per counter.
//  - whid LDS pinning dropped from P3 (no longer needed).
//  - Everything else (stages B/D/E, fences, atomics) identical to R7.

namespace {
constexpr int kB = 16, kT = 32, kF = 8, kS = 256, kH = 512;
constexpr int NBLK = 256, NTHR = 256;

// ws u32 counter layout (all < 1024, zeroed by 4KB memset):
//   half h sub-counter g: [h*256 + g*32], g in [0,8)
//   group-16 counter for b_att: [512 + b_att*32]
//   prologue grid counter: [1016]

// ws float offsets.
constexpr int OFF_AEH   = 1024;                   // [512][256] u32 attn_W[:,512:]
constexpr int OFF_WHID  = OFF_AEH + 131072;       // [512][256] u32 attn_W[:,:512]
constexpr int OFF_WIH0  = OFF_WHID + 131072;      // [1536][260] u32
constexpr int OFF_WHH0  = OFF_WIH0 + 399360;      // [1536][256] u32
constexpr int OFF_WIH1  = OFF_WHH0 + 393216;      // [1536][256] u32
constexpr int OFF_WHH1  = OFF_WIH1 + 393216;      // [1536][256] u32
constexpr int OFF_ENCH  = OFF_WHH1 + 393216;      // [4096][256] u32 enc f16
constexpr int OFF_ENCP  = OFF_ENCH + 1048576;     // [4096][256] u32 enc_proj f16
constexpr int OFF_HIDP  = OFF_ENCP + 1048576;     // [16][512] f32
constexpr int OFF_WEIA  = OFF_HIDP + 8192;        // [2][16][512] f32 accumulators
constexpr int OFF_LACC  = OFF_WEIA + 16384;       // [2][16] f32 accumulators
constexpr int OFF_OUTB  = OFF_LACC + 32;          // [2][16][8] f32
constexpr int OFF_H0C   = OFF_OUTB + 256;         // [2][16][256] u32
constexpr int OFF_H1C   = OFF_H0C + 8192;         // [2][16][256] u32
constexpr int OFF_XINC  = OFF_H1C + 8192;         // [2][16][8] f32
constexpr int OFF_OUTP  = OFF_XINC + 256;         // [16][128][8] f32

// LDS float/u32 offsets (L_WHID region retired; layout otherwise unchanged)
constexpr int L_WIH0 = 0;        // [12][264] u32 (260 + 4 zero pad)
constexpr int L_WHH0 = 3168;     // [12][256] u32
constexpr int L_BIH0 = 7264, L_BHH0 = 7276, L_BIH1 = 7288, L_BHH1 = 7300;
constexpr int L_OOW  = 7312;     // [8][4] f32 outW own cols
constexpr int L_VW   = 7344;     // [512] f32
constexpr int L_H1   = 7856;     // [8][264] u32 (persists A->E)
constexpr int L_HX   = 9968;     // [8][264] u32
constexpr int L_H0   = 12080;    // [8][264] u32
constexpr int L_HIDP = 14192;    // [512] f32
constexpr int L_ES   = 14704;    // [16]
constexpr int L_AX   = 14720;    // [96]
constexpr int L_AH   = 14816;    // [96]
constexpr int L_HS   = 14912;    // [32]
constexpr int L_XINL = 14944;    // [8]
constexpr int L_INV  = 14952;    // [8]
constexpr int LDS_FLOATS = 14960;
}  // namespace

typedef _Float16 h2 __attribute__((ext_vector_type(2)));
union U32H { unsigned u; h2 h; };

__device__ __forceinline__ float dot2(unsigned a, unsigned b, float acc) {
    U32H ua, ub; ua.u = a; ub.u = b;
#if __has_builtin(__builtin_amdgcn_fdot2)
    return __builtin_amdgcn_fdot2(ua.h, ub.h, acc, false);
#else
    return acc + (float)ua.h.x * (float)ub.h.x + (float)ua.h.y * (float)ub.h.y;
#endif
}
__device__ __forceinline__ unsigned packh2(float a, float b) {
    U32H u; u.h = h2{(_Float16)a, (_Float16)b}; return u.u;
}
__device__ __forceinline__ float fsig(float x) { return 1.0f / (1.0f + __expf(-x)); }
__device__ __forceinline__ float ftanhf(float x) {
    float e = __expf(2.0f * x);
    return 1.0f - 2.0f / (e + 1.0f);
}
// Uncached per-access comm ops (sc0 sc1 -> coherence point).
__device__ __forceinline__ float cload(const float* p) {
    return __hip_atomic_load(p, __ATOMIC_RELAXED, __HIP_MEMORY_SCOPE_SYSTEM);
}
__device__ __forceinline__ void cstore(float* p, float v) {
    __hip_atomic_store(p, v, __ATOMIC_RELAXED, __HIP_MEMORY_SCOPE_SYSTEM);
}
__device__ __forceinline__ unsigned ucload(const unsigned* p) {
    return __hip_atomic_load(p, __ATOMIC_RELAXED, __HIP_MEMORY_SCOPE_SYSTEM);
}

// Single-counter barrier (prologue grid + group-16). Fences as validated.
__device__ __forceinline__ void bar_sync(unsigned* cnt, unsigned target) {
    __syncthreads();
    if (threadIdx.x == 0) {
        __builtin_amdgcn_fence(__ATOMIC_RELEASE, "workgroup");
        __builtin_amdgcn_s_waitcnt(0);
        __hip_atomic_fetch_add(cnt, 1u, __ATOMIC_RELAXED, __HIP_MEMORY_SCOPE_SYSTEM);
        while (__hip_atomic_load(cnt, __ATOMIC_RELAXED, __HIP_MEMORY_SCOPE_SYSTEM) < target)
            __builtin_amdgcn_s_sleep(1);
        __builtin_amdgcn_fence(__ATOMIC_ACQUIRE, "workgroup");
    }
    __syncthreads();
}

// Half-grid tree barrier: 8 sub-counters (128B apart), 16 adds each.
// target = 16 * (barrier epoch).
__device__ __forceinline__ void bar_half_tree(unsigned* base, int grp, unsigned target) {
    __syncthreads();
    if (threadIdx.x == 0) {
        __builtin_amdgcn_fence(__ATOMIC_RELEASE, "workgroup");
        __builtin_amdgcn_s_waitcnt(0);
        __hip_atomic_fetch_add(&base[grp * 32], 1u, __ATOMIC_RELAXED, __HIP_MEMORY_SCOPE_SYSTEM);
        for (;;) {
            unsigned ok = 1u;
#pragma unroll
            for (int g = 0; g < 8; ++g)
                ok &= (unsigned)(__hip_atomic_load(&base[g * 32], __ATOMIC_RELAXED,
                                                   __HIP_MEMORY_SCOPE_SYSTEM) >= target);
            if (ok) break;
            __builtin_amdgcn_s_sleep(1);
        }
        __builtin_amdgcn_fence(__ATOMIC_ACQUIRE, "workgroup");
    }
    __syncthreads();
}

// Prologue barrier: one agent-scope wbl2 (release) / inv (acquire) per block.
__device__ __forceinline__ void bar_sync_flush(unsigned* cnt, unsigned target) {
    __syncthreads();
    if (threadIdx.x == 0) {
        __builtin_amdgcn_fence(__ATOMIC_RELEASE, "agent");
        __hip_atomic_fetch_add(cnt, 1u, __ATOMIC_RELAXED, __HIP_MEMORY_SCOPE_SYSTEM);
        while (__hip_atomic_load(cnt, __ATOMIC_RELAXED, __HIP_MEMORY_SCOPE_SYSTEM) < target)
            __builtin_amdgcn_s_sleep(8);
        __builtin_amdgcn_fence(__ATOMIC_ACQUIRE, "agent");
    }
    __syncthreads();
}

__global__ __launch_bounds__(NTHR) void decoder_kernel(
    const float* __restrict__ target, const float* __restrict__ hidden0,
    const float* __restrict__ enc, const float* __restrict__ attn_W,
    const float* __restrict__ attn_b, const float* __restrict__ v_w,
    const float* __restrict__ Wih0, const float* __restrict__ Whh0,
    const float* __restrict__ bih0, const float* __restrict__ bhh0,
    const float* __restrict__ Wih1, const float* __restrict__ Whh1,
    const float* __restrict__ bih1, const float* __restrict__ bhh1,
    const float* __restrict__ outW, const float* __restrict__ outBias,
    float* __restrict__ out, float* __restrict__ ws) {
    const int tid = threadIdx.x, bid = blockIdx.x;
    const int half = bid >> 7, j = bid & 127;
    const int bloc = j >> 4, sgrp = j & 15;
    const int b_att = half * 8 + bloc;
    unsigned* hcnt = (unsigned*)ws + half * 256;      // 8 sub-counters, stride 32
    unsigned* gcnt = (unsigned*)ws + 512 + b_att * 32;
    unsigned* gridCnt = (unsigned*)ws + 1016;
    unsigned hbars = 0;

    unsigned* aehU  = (unsigned*)(ws + OFF_AEH);
    unsigned* whidU = (unsigned*)(ws + OFF_WHID);
    unsigned* wih0U = (unsigned*)(ws + OFF_WIH0);
    unsigned* whh0U = (unsigned*)(ws + OFF_WHH0);
    unsigned* wih1U = (unsigned*)(ws + OFF_WIH1);
    unsigned* whh1U = (unsigned*)(ws + OFF_WHH1);
    unsigned* encU  = (unsigned*)(ws + OFF_ENCH);
    unsigned* encpU = (unsigned*)(ws + OFF_ENCP);
    float* hidP  = ws + OFF_HIDP;
    float* weiA  = ws + OFF_WEIA;
    float* lacc  = ws + OFF_LACC;
    float* outBs = ws + OFF_OUTB;
    unsigned* h0cU = (unsigned*)(ws + OFF_H0C);
    unsigned* h1cU = (unsigned*)(ws + OFF_H1C);
    float* xinC = ws + OFF_XINC;
    float* outP = ws + OFF_OUTP;

    __shared__ __align__(16) float lds[LDS_FLOATS];
    unsigned* ldsU = (unsigned*)lds;
    const int gtid = bid * NTHR + tid;

    // ===================== P1: f16 pack + state + accumulator init (plain) ====
    for (int i = gtid; i < 131072; i += NBLK * NTHR) {
        const int jr = i >> 8, p = i & 255;
        aehU[i]  = packh2(attn_W[jr * 1024 + 512 + 2 * p], attn_W[jr * 1024 + 513 + 2 * p]);
        whidU[i] = packh2(attn_W[jr * 1024 + 2 * p], attn_W[jr * 1024 + 1 + 2 * p]);
    }
    for (int i = gtid; i < 399360; i += NBLK * NTHR)
        wih0U[i] = packh2(Wih0[2 * i], Wih0[2 * i + 1]);
    for (int i = gtid; i < 393216; i += NBLK * NTHR) {
        whh0U[i] = packh2(Whh0[2 * i], Whh0[2 * i + 1]);
        wih1U[i] = packh2(Wih1[2 * i], Wih1[2 * i + 1]);
        whh1U[i] = packh2(Whh1[2 * i], Whh1[2 * i + 1]);
    }
    for (int i = gtid; i < 1048576; i += NBLK * NTHR)
        encU[i] = packh2(enc[2 * i], enc[2 * i + 1]);
    if (gtid < 4096) {
        const int bb = gtid >> 8, p = gtid & 255;
        h0cU[gtid] = packh2(hidden0[bb * 512 + 2 * p], hidden0[bb * 512 + 2 * p + 1]);
        h1cU[gtid] = packh2(hidden0[8192 + bb * 512 + 2 * p], hidden0[8192 + bb * 512 + 2 * p + 1]);
    }
    if (gtid < 128) {
        const int bb = gtid >> 3, f = gtid & 7;
        xinC[gtid] = target[bb * 256 + f];
    }
    for (int i = gtid; i < 16672; i += NBLK * NTHR)  // weiA + lacc + outBs zero
        ws[OFF_WEIA + i] = 0.f;
    bar_sync_flush(gridCnt, NBLK);  // one wbl2/inv per block

    // ===================== P2: enc_proj for own (b_att, 16 s) =================
    {
        for (int i = 0; i < 16; ++i) {
            const int idx = tid + i * 256;
            const int s = idx >> 8, p = idx & 255;
            ldsU[idx] = encU[(b_att * 256 + sgrp * 16 + s) * 256 + p];
        }
        __syncthreads();
        float a0[16], a1[16];
        const float bb0 = attn_b[2 * tid], bb1 = attn_b[2 * tid + 1];
#pragma unroll
        for (int s = 0; s < 16; ++s) { a0[s] = bb0; a1[s] = bb1; }
        const unsigned* w0 = &aehU[(2 * tid) * 256];
        const unsigned* w1 = &aehU[(2 * tid + 1) * 256];
        for (int p = 0; p < 256; ++p) {
            const unsigned ww0 = w0[p], ww1 = w1[p];
#pragma unroll
            for (int s = 0; s < 16; ++s) {
                const unsigned e = ldsU[s * 256 + p];
                a0[s] = dot2(e, ww0, a0[s]);
                a1[s] = dot2(e, ww1, a1[s]);
            }
        }
        for (int s = 0; s < 16; ++s)  // self-read only
            encpU[(b_att * 256 + sgrp * 16 + s) * 256 + tid] = packh2(a0[s], a1[s]);
        __syncthreads();
    }

    // ===================== P3: pin layer-0 weights + biases + outW in LDS =====
    for (int gh = 0; gh < 12; ++gh) {
        const int grow = (gh >> 2) * 512 + j * 4 + (gh & 3);
        for (int p = tid; p < 260; p += 256) ldsU[L_WIH0 + gh * 264 + p] = wih0U[grow * 260 + p];
        if (tid < 4) ldsU[L_WIH0 + gh * 264 + 260 + tid] = 0u;
        ldsU[L_WHH0 + gh * 256 + tid] = whh0U[grow * 256 + tid];
    }
    if (tid < 12) {
        const int grow = (tid >> 2) * 512 + j * 4 + (tid & 3);
        lds[L_BIH0 + tid] = bih0[grow]; lds[L_BHH0 + tid] = bhh0[grow];
        lds[L_BIH1 + tid] = bih1[grow]; lds[L_BHH1 + tid] = bhh1[grow];
    }
    if (tid < 32) lds[L_OOW + tid] = outW[(tid >> 2) * 1032 + j * 4 + (tid & 3)];
    lds[L_VW + tid] = v_w[tid];
    lds[L_VW + 256 + tid] = v_w[256 + tid];
    __syncthreads();

    // ===================== main recurrence: A | B | D | E =====================
    for (int t = 0; t < kT; ++t) {
        const int par = t & 1;

        // ---- A: finalize out[t-1] + stage h1 (8 batches) + own hidP slice ----
        if (t > 0 && sgrp == 15 && tid < 64) {
            const int f = tid >> 3, sub = tid & 7;
            float acc = 0.f;
            for (int i = 0; i < 16; ++i)
                acc += cload(&outP[(b_att * 128 + sub * 16 + i) * 8 + f]);
            acc += __shfl_down(acc, 4, 8); acc += __shfl_down(acc, 2, 8); acc += __shfl_down(acc, 1, 8);
            if (sub == 0) {
                acc += cload(&outBs[(par ^ 1) * 128 + b_att * 8 + f]);
                const float o = fmaxf(acc, 0.f);
                out[b_att * 256 + (t - 1) * 8 + f] = o;
                cstore(&xinC[par * 128 + b_att * 8 + f], o);
            }
        }
        for (int i = 0; i < 8; ++i) {
            const int idx = tid + i * 256;
            const int bb = idx >> 8, p = idx & 255;
            ldsU[L_H1 + bb * 264 + p] = ucload(&h1cU[par * 4096 + (half * 8 + bb) * 256 + p]);
        }
        __syncthreads();
        {
            // hidP rows [sgrp*32, +32) for OWN b_att; whid rows straight from L2.
            const int r = tid >> 3, sub = tid & 7;
            const uint4* wrow = (const uint4*)&whidU[(sgrp * 32 + r) * 256 + sub * 32];
            const uint4* h1p = (const uint4*)&ldsU[L_H1 + bloc * 264 + sub * 32];
            float acc = 0.f;
#pragma unroll
            for (int k4 = 0; k4 < 8; ++k4) {
                const uint4 hv = h1p[k4], wv = wrow[k4];
                acc = dot2(hv.x, wv.x, acc); acc = dot2(hv.y, wv.y, acc);
                acc = dot2(hv.z, wv.z, acc); acc = dot2(hv.w, wv.w, acc);
            }
            acc += __shfl_down(acc, 4, 8); acc += __shfl_down(acc, 2, 8); acc += __shfl_down(acc, 1, 8);
            if (sub == 0) cstore(&hidP[b_att * 512 + sgrp * 32 + r], acc);
        }
        bar_sync(gcnt, 16u * (t + 1));  // group-16 barrier (own b_att)

        // ---- B: energy (16 s) + exp + atomicAdd weighted/L ----
        lds[L_HIDP + tid] = cload(&hidP[b_att * 512 + tid]);
        lds[L_HIDP + 256 + tid] = cload(&hidP[b_att * 512 + 256 + tid]);
        __syncthreads();
        {
            const int sloc = tid >> 4, sub = tid & 15;
            const unsigned* ep = &encpU[(b_att * 256 + sgrp * 16 + sloc) * 256];
            float acc = 0.f;
#pragma unroll 4
            for (int k2 = 0; k2 < 16; ++k2) {
                const int p = k2 * 16 + sub;
                U32H u; u.u = ep[p];
                acc += lds[L_VW + 2 * p] * ftanhf((float)u.h.x + lds[L_HIDP + 2 * p]);
                acc += lds[L_VW + 2 * p + 1] * ftanhf((float)u.h.y + lds[L_HIDP + 2 * p + 1]);
            }
            acc += __shfl_down(acc, 8, 16); acc += __shfl_down(acc, 4, 16);
            acc += __shfl_down(acc, 2, 16); acc += __shfl_down(acc, 1, 16);
            if (sub == 0) lds[L_ES + sloc] = __expf(acc);  // |score|<=~20: fp32-safe
        }
        __syncthreads();
        {
            float wp0 = 0.f, wp1 = 0.f;
            const unsigned* er = &encU[(b_att * 256 + sgrp * 16) * 256 + tid];
#pragma unroll
            for (int sl = 0; sl < 16; ++sl) {
                U32H u; u.u = er[sl * 256];
                const float es = lds[L_ES + sl];
                wp0 += es * (float)u.h.x; wp1 += es * (float)u.h.y;
            }
            atomicAdd(&weiA[par * 8192 + b_att * 512 + 2 * tid], wp0);
            atomicAdd(&weiA[par * 8192 + b_att * 512 + 2 * tid + 1], wp1);
            if (tid == 0) {
                float l = 0.f;
#pragma unroll
                for (int i = 0; i < 16; ++i) l += lds[L_ES + i];
                atomicAdd(&lacc[par * 16 + b_att], l);
            }
        }
        bar_half_tree(hcnt, bloc, 16u * (++hbars));

        // ---- D: normalize wei + GRU0 rows + out base term ----
        if (tid < 8) {
            const float L = cload(&lacc[par * 16 + half * 8 + tid]);
            lds[L_INV + tid] = 1.f / L;
        }
        if (sgrp == 14 && tid >= 8 && tid < 16)
            lds[L_XINL + tid - 8] = cload(&xinC[par * 128 + b_att * 8 + (tid - 8)]);
        if (tid >= 32 && tid < 64) {
            const int bb = (tid - 32) >> 2, q4 = (tid - 32) & 3;
            const float f0 = cload(&xinC[par * 128 + (half * 8 + bb) * 8 + 2 * q4]);
            const float f1 = cload(&xinC[par * 128 + (half * 8 + bb) * 8 + 2 * q4 + 1]);
            ldsU[L_HX + bb * 264 + q4] = packh2(f0, f1);
            ldsU[L_HX + bb * 264 + 260 + q4] = 0u;  // zero tail pad
        }
        for (int i = 0; i < 8; ++i) {
            const int idx = tid + i * 256;
            const int bb = idx >> 8, p = idx & 255;
            ldsU[L_H0 + bb * 264 + p] = ucload(&h0cU[par * 4096 + (half * 8 + bb) * 256 + p]);
        }
        __syncthreads();
        for (int i = 0; i < 8; ++i) {
            const int idx = tid + i * 256;
            const int bb = idx >> 8, p = idx & 255;
            const float w0 = cload(&weiA[par * 8192 + (half * 8 + bb) * 512 + 2 * p]);
            const float w1 = cload(&weiA[par * 8192 + (half * 8 + bb) * 512 + 2 * p + 1]);
            const float inv = lds[L_INV + bb];
            ldsU[L_HX + bb * 264 + 4 + p] = packh2(w0 * inv, w1 * inv);
        }
        __syncthreads();
        if (tid < 192) {
            const int u = tid >> 1, sub = tid & 1;
            const int bb = u & 7, gh = u >> 3;
            const uint4* wx = (const uint4*)&ldsU[L_WIH0 + gh * 264 + sub * 132];
            const uint4* xp = (const uint4*)&ldsU[L_HX + bb * 264 + sub * 132];
            float ax = 0.f;
#pragma unroll 11
            for (int k4 = 0; k4 < 33; ++k4) {
                const uint4 xv = xp[k4], wv = wx[k4];
                ax = dot2(xv.x, wv.x, ax); ax = dot2(xv.y, wv.y, ax);
                ax = dot2(xv.z, wv.z, ax); ax = dot2(xv.w, wv.w, ax);
            }
            const uint4* wh = (const uint4*)&ldsU[L_WHH0 + gh * 256 + sub * 128];
            const uint4* hp = (const uint4*)&ldsU[L_H0 + bb * 264 + sub * 128];
            float ah = 0.f;
#pragma unroll 8
            for (int k4 = 0; k4 < 32; ++k4) {
                const uint4 hv = hp[k4], wv = wh[k4];
                ah = dot2(hv.x, wv.x, ah); ah = dot2(hv.y, wv.y, ah);
                ah = dot2(hv.z, wv.z, ah); ah = dot2(hv.w, wv.w, ah);
            }
            ax += __shfl_down(ax, 1, 2); ah += __shfl_down(ah, 1, 2);
            if (sub == 0) {
                lds[L_AX + gh * 8 + bb] = ax + lds[L_BIH0 + gh];
                lds[L_AH + gh * 8 + bb] = ah + lds[L_BHH0 + gh];
            }
        }
        __syncthreads();
        if (tid < 32) {
            const int hr = tid >> 3, bb = tid & 7;
            const float r = fsig(lds[L_AX + hr * 8 + bb] + lds[L_AH + hr * 8 + bb]);
            const float z = fsig(lds[L_AX + (4 + hr) * 8 + bb] + lds[L_AH + (4 + hr) * 8 + bb]);
            const float n = ftanhf(lds[L_AX + (8 + hr) * 8 + bb] + r * lds[L_AH + (8 + hr) * 8 + bb]);
            U32H u; u.u = ldsU[L_H0 + bb * 264 + j * 2 + (hr >> 1)];
            const float hold = (hr & 1) ? (float)u.h.y : (float)u.h.x;
            lds[L_HS + hr * 8 + bb] = (1.f - z) * n + z * hold;
        }
        if (sgrp == 14 && tid >= 64 && tid < 128) {
            const int f = (tid - 64) >> 3, sub2 = tid & 7;
            float acc = 0.f;
            const float* ow = &outW[f * 1032 + 512 + sub2 * 64];
#pragma unroll 8
            for (int p2 = 0; p2 < 32; ++p2) {
                U32H u; u.u = ldsU[L_HX + bloc * 264 + 4 + sub2 * 32 + p2];
                acc += ow[2 * p2] * (float)u.h.x + ow[2 * p2 + 1] * (float)u.h.y;
            }
            acc += __shfl_down(acc, 4, 8); acc += __shfl_down(acc, 2, 8); acc += __shfl_down(acc, 1, 8);
            if (sub2 == 0) {
#pragma unroll
                for (int ff = 0; ff < 8; ++ff)
                    acc += outW[f * 1032 + 1024 + ff] * lds[L_XINL + ff];
                cstore(&outBs[par * 128 + b_att * 8 + f], acc + outBias[f]);
            }
        }
        __syncthreads();
        if (tid < 16) {
            const int pp = tid >> 3, bb = tid & 7;
            __hip_atomic_store(&h0cU[(par ^ 1) * 4096 + (half * 8 + bb) * 256 + j * 2 + pp],
                               packh2(lds[L_HS + (2 * pp) * 8 + bb], lds[L_HS + (2 * pp + 1) * 8 + bb]),
                               __ATOMIC_RELAXED, __HIP_MEMORY_SCOPE_SYSTEM);
        }
        bar_half_tree(hcnt, bloc, 16u * (++hbars));

        // ---- E: GRU1 rows + outP partials + accumulator re-zero ----
        for (int i = 0; i < 8; ++i) {
            const int idx = tid + i * 256;
            const int bb = idx >> 8, p = idx & 255;
            ldsU[L_HX + bb * 264 + p] = ucload(&h0cU[(par ^ 1) * 4096 + (half * 8 + bb) * 256 + p]);
        }
        __syncthreads();
        if (tid < 192) {
            const int u = tid >> 1, sub = tid & 1;
            const int bb = u & 7, gh = u >> 3;
            const int grow = (gh >> 2) * 512 + j * 4 + (gh & 3);
            const uint4* wx = (const uint4*)&wih1U[grow * 256 + sub * 128];
            const uint4* xp = (const uint4*)&ldsU[L_HX + bb * 264 + sub * 128];
            float ax = 0.f;
#pragma unroll 8
            for (int k4 = 0; k4 < 32; ++k4) {
                const uint4 xv = xp[k4], wv = wx[k4];
                ax = dot2(xv.x, wv.x, ax); ax = dot2(xv.y, wv.y, ax);
                ax = dot2(xv.z, wv.z, ax); ax = dot2(xv.w, wv.w, ax);
            }
            const uint4* wh = (const uint4*)&whh1U[grow * 256 + sub * 128];
            const uint4* hp = (const uint4*)&ldsU[L_H1 + bb * 264 + sub * 128];
            float ah = 0.f;
#pragma unroll 8
            for (int k4 = 0; k4 < 32; ++k4) {
                const uint4 hv = hp[k4], wv = wh[k4];
                ah = dot2(hv.x, wv.x, ah); ah = dot2(hv.y, wv.y, ah);
                ah = dot2(hv.z, wv.z, ah); ah = dot2(hv.w, wv.w, ah);
            }
            ax += __shfl_down(ax, 1, 2); ah += __shfl_down(ah, 1, 2);
            if (sub == 0) {
                lds[L_AX + gh * 8 + bb] = ax + lds[L_BIH1 + gh];
                lds[L_AH + gh * 8 + bb] = ah + lds[L_BHH1 + gh];
            }
        }
        __syncthreads();
        if (tid < 32) {
            const int hr = tid >> 3, bb = tid & 7;
            const float r = fsig(lds[L_AX + hr * 8 + bb] + lds[L_AH + hr * 8 + bb]);
            const float z = fsig(lds[L_AX + (4 + hr) * 8 + bb] + lds[L_AH + (4 + hr) * 8 + bb]);
            const float n = ftanhf(lds[L_AX + (8 + hr) * 8 + bb] + r * lds[L_AH + (8 + hr) * 8 + bb]);
            U32H u; u.u = ldsU[L_H1 + bb * 264 + j * 2 + (hr >> 1)];
            const float hold = (hr & 1) ? (float)u.h.y : (float)u.h.x;
            lds[L_HS + hr * 8 + bb] = (1.f - z) * n + z * hold;
        }
        __syncthreads();
        if (tid < 16) {
            const int pp = tid >> 3, bb = tid & 7;
            __hip_atomic_store(&h1cU[(par ^ 1) * 4096 + (half * 8 + bb) * 256 + j * 2 + pp],
                               packh2(lds[L_HS + (2 * pp) * 8 + bb], lds[L_HS + (2 * pp + 1) * 8 + bb]),
                               __ATOMIC_RELAXED, __HIP_MEMORY_SCOPE_SYSTEM);
        }
        if (tid < 64) {
            const int f = tid >> 3, bb = tid & 7;
            float acc = 0.f;
#pragma unroll
            for (int hr = 0; hr < 4; ++hr)
                acc += lds[L_OOW + f * 4 + hr] * lds[L_HS + hr * 8 + bb];
            cstore(&outP[((half * 8 + bb) * 128 + j) * 8 + f], acc);
        }
        if (tid < 32) cstore(&weiA[par * 8192 + half * 4096 + j * 32 + tid], 0.f);
        if (sgrp == 0 && tid == 0) cstore(&lacc[par * 16 + b_att], 0.f);
        bar_half_tree(hcnt, bloc, 16u * (++hbars));
    }

    // ---- epilogue: finalize out[31] (par(31) = 1) ----
    if (sgrp == 15 && tid < 64) {
        const int f = tid >> 3, sub = tid & 7;
        float acc = 0.f;
        for (int i = 0; i < 16; ++i)
            acc += cload(&outP[(b_att * 128 + sub * 16 + i) * 8 + f]);
        acc += __shfl_down(acc, 4, 8); acc += __shfl_down(acc, 2, 8); acc += __shfl_down(acc, 1, 8);
        if (sub == 0) {
            acc += cload(&outBs[1 * 128 + b_att * 8 + f]);
            out[b_att * 256 + 31 * 8 + f] = fmaxf(acc, 0.f);
        }
    }
}

extern "C" void kernel_launch(void* const* d_in, const int* in_sizes, int n_in,
                              void* d_out, int out_size, void* d_ws, size_t ws_size,
                              hipStream_t stream) {
    (void)in_sizes; (void)n_in; (void)out_size; (void)ws_size;
    hipMemsetAsync(d_ws, 0, 4096, stream);  // zero barrier counters
    decoder_kernel<<<NBLK, NTHR, 0, stream>>>(
        (const float*)d_in[0], (const float*)d_in[1], (const float*)d_in[2],
        (const float*)d_in[3], (const float*)d_in[4], (const float*)d_in[5],
        (const float*)d_in[6], (const float*)d_in[7], (const float*)d_in[8],
        (const float*)d_in[9], (const float*)d_in[10], (const float*)d_in[11],
        (const float*)d_in[12], (const float*)d_in[13], (const float*)d_in[14],
        (const float*)d_in[15], (float*)d_out, (float*)d_ws);
}

// Round 3
// 1165.093 us; speedup vs baseline: 1.0168x; 1.0033x over previous
//
#include <hip/hip_runtime.h>

// DecoderWithAttention: B=16, T=32, F=8, S_ENC=256, H=512, L=2.
// R9: fully decoupled per-batch groups (theory: half-wide lockstep coupling,
// not arrival serialization, is the ~31us/step cost).
//  - 16 groups x 16 blocks. Block (b, s): bid = b*16 + s (s varies fastest ->
//    XCD bid%8 hosts 2 s-slices, weight working set ~1.6MB/XCD, L2-resident).
//  - Block (b,s) owns h-rows [s*32,+32) of batch b for GRU0 AND GRU1 (gate
//    rows g*512+s*32+r streamed from L2 each step), hidP rows [s*32,+32),
//    attention s-slice [s*16,+16) (as before).
//  - ALL 4 barriers/step are group-16 (own-batch counter). No half/grid sync
//    in the main loop; groups drift independently -> skew doesn't compound.
//  - GRU weights no longer LDS-pinned (per-block row set too big); biases +
//    own outW cols + v_w pinned. LDS ~16KB.
//  - Fences/atomics/prologue identical to validated R7/R8 structure.

namespace {
constexpr int NBLK = 256, NTHR = 256;

// ws u32 counters (zeroed by 4KB memset): group b counter at [b*32]; grid at [1016].

// ws float offsets (weight regions identical to R8).
constexpr int OFF_AEH   = 1024;                   // [512][256] u32 attn_W[:,512:]
constexpr int OFF_WHID  = OFF_AEH + 131072;       // [512][256] u32 attn_W[:,:512]
constexpr int OFF_WIH0  = OFF_WHID + 131072;      // [1536][260] u32
constexpr int OFF_WHH0  = OFF_WIH0 + 399360;      // [1536][256] u32
constexpr int OFF_WIH1  = OFF_WHH0 + 393216;      // [1536][256] u32
constexpr int OFF_WHH1  = OFF_WIH1 + 393216;      // [1536][256] u32
constexpr int OFF_ENCH  = OFF_WHH1 + 393216;      // [4096][256] u32 enc f16
constexpr int OFF_ENCP  = OFF_ENCH + 1048576;     // [4096][256] u32 enc_proj f16
constexpr int OFF_HIDP  = OFF_ENCP + 1048576;     // [16][512] f32
constexpr int OFF_WEIA  = OFF_HIDP + 8192;        // [2][16][512] f32 accumulators
constexpr int OFF_LACC  = OFF_WEIA + 16384;       // [2][16] f32
constexpr int OFF_OUTB  = OFF_LACC + 32;          // [2][16][8] f32
constexpr int OFF_H0C   = OFF_OUTB + 256;         // [2][16][256] u32
constexpr int OFF_H1C   = OFF_H0C + 8192;         // [2][16][256] u32
constexpr int OFF_XINC  = OFF_H1C + 8192;         // [2][16][8] f32
constexpr int OFF_OUTP  = OFF_XINC + 256;         // [16][16][8] f32

// LDS float/u32 offsets. P2 staging needs [0..4096).
constexpr int L_H1   = 0;      // [264] u32 h1(t) full (persists A->E)
constexpr int L_HX   = 264;    // [264] u32 (xin4 | weighted256 | pad4) / h0new in E
constexpr int L_H0   = 528;    // [264] u32 h0(t) full
constexpr int L_HIDP = 792;    // [512] f32
constexpr int L_ES   = 1304;   // [16]
constexpr int L_AX   = 1320;   // [96]
constexpr int L_AH   = 1416;   // [96]
constexpr int L_HS   = 1512;   // [32]
constexpr int L_BIH0 = 1544, L_BHH0 = 1640, L_BIH1 = 1736, L_BHH1 = 1832;  // [96]
constexpr int L_OOW  = 1928;   // [8][32] f32 outW own cols
constexpr int L_VW   = 2184;   // [512] f32
constexpr int L_XINL = 2696;   // [8]
constexpr int L_INV  = 2704;   // [8]
constexpr int LDS_FLOATS = 4096;
}  // namespace

typedef _Float16 h2 __attribute__((ext_vector_type(2)));
union U32H { unsigned u; h2 h; };

__device__ __forceinline__ float dot2(unsigned a, unsigned b, float acc) {
    U32H ua, ub; ua.u = a; ub.u = b;
#if __has_builtin(__builtin_amdgcn_fdot2)
    return __builtin_amdgcn_fdot2(ua.h, ub.h, acc, false);
#else
    return acc + (float)ua.h.x * (float)ub.h.x + (float)ua.h.y * (float)ub.h.y;
#endif
}
__device__ __forceinline__ unsigned packh2(float a, float b) {
    U32H u; u.h = h2{(_Float16)a, (_Float16)b}; return u.u;
}
__device__ __forceinline__ float fsig(float x) { return 1.0f / (1.0f + __expf(-x)); }
__device__ __forceinline__ float ftanhf(float x) {
    float e = __expf(2.0f * x);
    return 1.0f - 2.0f / (e + 1.0f);
}
// Uncached per-access comm ops (sc0 sc1 -> coherence point).
__device__ __forceinline__ float cload(const float* p) {
    return __hip_atomic_load(p, __ATOMIC_RELAXED, __HIP_MEMORY_SCOPE_SYSTEM);
}
__device__ __forceinline__ void cstore(float* p, float v) {
    __hip_atomic_store(p, v, __ATOMIC_RELAXED, __HIP_MEMORY_SCOPE_SYSTEM);
}
__device__ __forceinline__ unsigned ucload(const unsigned* p) {
    return __hip_atomic_load(p, __ATOMIC_RELAXED, __HIP_MEMORY_SCOPE_SYSTEM);
}

// Group/prologue barrier (validated fence structure).
__device__ __forceinline__ void bar_sync(unsigned* cnt, unsigned target) {
    __syncthreads();
    if (threadIdx.x == 0) {
        __builtin_amdgcn_fence(__ATOMIC_RELEASE, "workgroup");
        __builtin_amdgcn_s_waitcnt(0);
        __hip_atomic_fetch_add(cnt, 1u, __ATOMIC_RELAXED, __HIP_MEMORY_SCOPE_SYSTEM);
        while (__hip_atomic_load(cnt, __ATOMIC_RELAXED, __HIP_MEMORY_SCOPE_SYSTEM) < target)
            __builtin_amdgcn_s_sleep(1);
        __builtin_amdgcn_fence(__ATOMIC_ACQUIRE, "workgroup");
    }
    __syncthreads();
}

// Prologue barrier: one agent-scope wbl2 (release) / inv (acquire) per block.
__device__ __forceinline__ void bar_sync_flush(unsigned* cnt, unsigned target) {
    __syncthreads();
    if (threadIdx.x == 0) {
        __builtin_amdgcn_fence(__ATOMIC_RELEASE, "agent");
        __hip_atomic_fetch_add(cnt, 1u, __ATOMIC_RELAXED, __HIP_MEMORY_SCOPE_SYSTEM);
        while (__hip_atomic_load(cnt, __ATOMIC_RELAXED, __HIP_MEMORY_SCOPE_SYSTEM) < target)
            __builtin_amdgcn_s_sleep(8);
        __builtin_amdgcn_fence(__ATOMIC_ACQUIRE, "agent");
    }
    __syncthreads();
}

__global__ __launch_bounds__(NTHR) void decoder_kernel(
    const float* __restrict__ target, const float* __restrict__ hidden0,
    const float* __restrict__ enc, const float* __restrict__ attn_W,
    const float* __restrict__ attn_b, const float* __restrict__ v_w,
    const float* __restrict__ Wih0, const float* __restrict__ Whh0,
    const float* __restrict__ bih0, const float* __restrict__ bhh0,
    const float* __restrict__ Wih1, const float* __restrict__ Whh1,
    const float* __restrict__ bih1, const float* __restrict__ bhh1,
    const float* __restrict__ outW, const float* __restrict__ outBias,
    float* __restrict__ out, float* __restrict__ ws) {
    const int tid = threadIdx.x, bid = blockIdx.x;
    const int b = bid >> 4, s = bid & 15;   // group (batch) / slice
    unsigned* gcnt = (unsigned*)ws + b * 32;
    unsigned* gridCnt = (unsigned*)ws + 1016;
    unsigned gb = 0;

    unsigned* aehU  = (unsigned*)(ws + OFF_AEH);
    unsigned* whidU = (unsigned*)(ws + OFF_WHID);
    unsigned* wih0U = (unsigned*)(ws + OFF_WIH0);
    unsigned* whh0U = (unsigned*)(ws + OFF_WHH0);
    unsigned* wih1U = (unsigned*)(ws + OFF_WIH1);
    unsigned* whh1U = (unsigned*)(ws + OFF_WHH1);
    unsigned* encU  = (unsigned*)(ws + OFF_ENCH);
    unsigned* encpU = (unsigned*)(ws + OFF_ENCP);
    float* hidP  = ws + OFF_HIDP;
    float* weiA  = ws + OFF_WEIA;
    float* lacc  = ws + OFF_LACC;
    float* outBs = ws + OFF_OUTB;
    unsigned* h0cU = (unsigned*)(ws + OFF_H0C);
    unsigned* h1cU = (unsigned*)(ws + OFF_H1C);
    float* xinC = ws + OFF_XINC;
    float* outP = ws + OFF_OUTP;

    __shared__ __align__(16) float lds[LDS_FLOATS];
    unsigned* ldsU = (unsigned*)lds;
    const int gtid = bid * NTHR + tid;

    // ===================== P1: f16 pack + state + accumulator init (plain) ====
    for (int i = gtid; i < 131072; i += NBLK * NTHR) {
        const int jr = i >> 8, p = i & 255;
        aehU[i]  = packh2(attn_W[jr * 1024 + 512 + 2 * p], attn_W[jr * 1024 + 513 + 2 * p]);
        whidU[i] = packh2(attn_W[jr * 1024 + 2 * p], attn_W[jr * 1024 + 1 + 2 * p]);
    }
    for (int i = gtid; i < 399360; i += NBLK * NTHR)
        wih0U[i] = packh2(Wih0[2 * i], Wih0[2 * i + 1]);
    for (int i = gtid; i < 393216; i += NBLK * NTHR) {
        whh0U[i] = packh2(Whh0[2 * i], Whh0[2 * i + 1]);
        wih1U[i] = packh2(Wih1[2 * i], Wih1[2 * i + 1]);
        whh1U[i] = packh2(Whh1[2 * i], Whh1[2 * i + 1]);
    }
    for (int i = gtid; i < 1048576; i += NBLK * NTHR)
        encU[i] = packh2(enc[2 * i], enc[2 * i + 1]);
    if (gtid < 4096) {
        const int bb = gtid >> 8, p = gtid & 255;
        h0cU[gtid] = packh2(hidden0[bb * 512 + 2 * p], hidden0[bb * 512 + 2 * p + 1]);
        h1cU[gtid] = packh2(hidden0[8192 + bb * 512 + 2 * p], hidden0[8192 + bb * 512 + 2 * p + 1]);
    }
    if (gtid < 128) {
        const int bb = gtid >> 3, f = gtid & 7;
        xinC[gtid] = target[bb * 256 + f];
    }
    for (int i = gtid; i < 16672; i += NBLK * NTHR)  // weiA + lacc + outBs zero
        ws[OFF_WEIA + i] = 0.f;
    bar_sync_flush(gridCnt, NBLK);  // one wbl2/inv per block

    // ===================== P2: enc_proj for own (b, 16 s) =====================
    {
        for (int i = 0; i < 16; ++i) {
            const int idx = tid + i * 256;
            const int sl = idx >> 8, p = idx & 255;
            ldsU[idx] = encU[(b * 256 + s * 16 + sl) * 256 + p];
        }
        __syncthreads();
        float a0[16], a1[16];
        const float bb0 = attn_b[2 * tid], bb1 = attn_b[2 * tid + 1];
#pragma unroll
        for (int sl = 0; sl < 16; ++sl) { a0[sl] = bb0; a1[sl] = bb1; }
        const unsigned* w0 = &aehU[(2 * tid) * 256];
        const unsigned* w1 = &aehU[(2 * tid + 1) * 256];
        for (int p = 0; p < 256; ++p) {
            const unsigned ww0 = w0[p], ww1 = w1[p];
#pragma unroll
            for (int sl = 0; sl < 16; ++sl) {
                const unsigned e = ldsU[sl * 256 + p];
                a0[sl] = dot2(e, ww0, a0[sl]);
                a1[sl] = dot2(e, ww1, a1[sl]);
            }
        }
        for (int sl = 0; sl < 16; ++sl)  // self-read only
            encpU[(b * 256 + s * 16 + sl) * 256 + tid] = packh2(a0[sl], a1[sl]);
        __syncthreads();
    }

    // ===================== P3: pin biases + own outW cols + v_w in LDS ========
    if (tid < 96) {
        const int grow = (tid >> 5) * 512 + s * 32 + (tid & 31);
        lds[L_BIH0 + tid] = bih0[grow]; lds[L_BHH0 + tid] = bhh0[grow];
        lds[L_BIH1 + tid] = bih1[grow]; lds[L_BHH1 + tid] = bhh1[grow];
    }
    {
        const int f = tid >> 5, r = tid & 31;
        lds[L_OOW + f * 32 + r] = outW[f * 1032 + s * 32 + r];
    }
    lds[L_VW + tid] = v_w[tid];
    lds[L_VW + 256 + tid] = v_w[256 + tid];
    __syncthreads();

    // ===================== main recurrence: A | B | D | E (group-local) =======
    for (int t = 0; t < 32; ++t) {
        const int par = t & 1;

        // ---- A: finalize out[t-1] (s==15) + stage h1 + own hidP slice ----
        if (t > 0 && s == 15 && tid < 64) {
            const int f = tid >> 3, sub = tid & 7;
            float acc = cload(&outP[(b * 16 + sub * 2) * 8 + f]) +
                        cload(&outP[(b * 16 + sub * 2 + 1) * 8 + f]);
            acc += __shfl_down(acc, 4, 8); acc += __shfl_down(acc, 2, 8); acc += __shfl_down(acc, 1, 8);
            if (sub == 0) {
                acc += cload(&outBs[(par ^ 1) * 128 + b * 8 + f]);
                const float o = fmaxf(acc, 0.f);
                out[b * 256 + (t - 1) * 8 + f] = o;
                cstore(&xinC[par * 128 + b * 8 + f], o);
            }
        }
        ldsU[L_H1 + tid] = ucload(&h1cU[par * 4096 + b * 256 + tid]);
        __syncthreads();
        {
            // hidP rows [s*32,+32) for own b; whid rows streamed from L2.
            const int r = tid >> 3, sub = tid & 7;
            const uint4* wrow = (const uint4*)&whidU[(s * 32 + r) * 256 + sub * 32];
            const uint4* h1p = (const uint4*)&ldsU[L_H1 + sub * 32];
            float acc = 0.f;
#pragma unroll
            for (int k4 = 0; k4 < 8; ++k4) {
                const uint4 hv = h1p[k4], wv = wrow[k4];
                acc = dot2(hv.x, wv.x, acc); acc = dot2(hv.y, wv.y, acc);
                acc = dot2(hv.z, wv.z, acc); acc = dot2(hv.w, wv.w, acc);
            }
            acc += __shfl_down(acc, 4, 8); acc += __shfl_down(acc, 2, 8); acc += __shfl_down(acc, 1, 8);
            if (sub == 0) cstore(&hidP[b * 512 + s * 32 + r], acc);
        }
        bar_sync(gcnt, 16u * (++gb));

        // ---- B: energy (16 s-rows) + exp + atomicAdd weighted/L ----
        lds[L_HIDP + tid] = cload(&hidP[b * 512 + tid]);
        lds[L_HIDP + 256 + tid] = cload(&hidP[b * 512 + 256 + tid]);
        __syncthreads();
        {
            const int sloc = tid >> 4, sub = tid & 15;
            const unsigned* ep = &encpU[(b * 256 + s * 16 + sloc) * 256];
            float acc = 0.f;
#pragma unroll 4
            for (int k2 = 0; k2 < 16; ++k2) {
                const int p = k2 * 16 + sub;
                U32H u; u.u = ep[p];
                acc += lds[L_VW + 2 * p] * ftanhf((float)u.h.x + lds[L_HIDP + 2 * p]);
                acc += lds[L_VW + 2 * p + 1] * ftanhf((float)u.h.y + lds[L_HIDP + 2 * p + 1]);
            }
            acc += __shfl_down(acc, 8, 16); acc += __shfl_down(acc, 4, 16);
            acc += __shfl_down(acc, 2, 16); acc += __shfl_down(acc, 1, 16);
            if (sub == 0) lds[L_ES + sloc] = __expf(acc);  // |score|<=~20: fp32-safe
        }
        __syncthreads();
        {
            float wp0 = 0.f, wp1 = 0.f;
            const unsigned* er = &encU[(b * 256 + s * 16) * 256 + tid];
#pragma unroll
            for (int sl = 0; sl < 16; ++sl) {
                U32H u; u.u = er[sl * 256];
                const float es = lds[L_ES + sl];
                wp0 += es * (float)u.h.x; wp1 += es * (float)u.h.y;
            }
            atomicAdd(&weiA[par * 8192 + b * 512 + 2 * tid], wp0);
            atomicAdd(&weiA[par * 8192 + b * 512 + 2 * tid + 1], wp1);
            if (tid == 0) {
                float l = 0.f;
#pragma unroll
                for (int i = 0; i < 16; ++i) l += lds[L_ES + i];
                atomicAdd(&lacc[par * 16 + b], l);
            }
        }
        bar_sync(gcnt, 16u * (++gb));

        // ---- D: normalize wei + GRU0 rows [s*32,+32) + out base (s==14) ----
        if (tid == 0) lds[L_INV] = 1.f / cload(&lacc[par * 16 + b]);
        if (s == 14 && tid >= 8 && tid < 16)
            lds[L_XINL + tid - 8] = cload(&xinC[par * 128 + b * 8 + (tid - 8)]);
        if (tid >= 32 && tid < 36) {
            const int q4 = tid - 32;
            const float f0 = cload(&xinC[par * 128 + b * 8 + 2 * q4]);
            const float f1 = cload(&xinC[par * 128 + b * 8 + 2 * q4 + 1]);
            ldsU[L_HX + q4] = packh2(f0, f1);
            ldsU[L_HX + 260 + q4] = 0u;  // zero tail pad
        }
        ldsU[L_H0 + tid] = ucload(&h0cU[par * 4096 + b * 256 + tid]);
        __syncthreads();
        {
            const float inv = lds[L_INV];
            const float w0 = cload(&weiA[par * 8192 + b * 512 + 2 * tid]);
            const float w1 = cload(&weiA[par * 8192 + b * 512 + 2 * tid + 1]);
            ldsU[L_HX + 4 + tid] = packh2(w0 * inv, w1 * inv);
        }
        __syncthreads();
        if (tid < 192) {
            const int u = tid >> 1, sub = tid & 1;
            const int gh = u >> 5, r = u & 31;
            const int grow = gh * 512 + s * 32 + r;
            const uint4* wx = (const uint4*)&wih0U[grow * 260 + sub * 132];
            const uint4* xp = (const uint4*)&ldsU[L_HX + sub * 132];
            float ax = 0.f;
#pragma unroll 11
            for (int k4 = 0; k4 < 33; ++k4) {
                const uint4 xv = xp[k4], wv = wx[k4];
                ax = dot2(xv.x, wv.x, ax); ax = dot2(xv.y, wv.y, ax);
                ax = dot2(xv.z, wv.z, ax); ax = dot2(xv.w, wv.w, ax);
            }
            const uint4* wh = (const uint4*)&whh0U[grow * 256 + sub * 128];
            const uint4* hp = (const uint4*)&ldsU[L_H0 + sub * 128];
            float ah = 0.f;
#pragma unroll 8
            for (int k4 = 0; k4 < 32; ++k4) {
                const uint4 hv = hp[k4], wv = wh[k4];
                ah = dot2(hv.x, wv.x, ah); ah = dot2(hv.y, wv.y, ah);
                ah = dot2(hv.z, wv.z, ah); ah = dot2(hv.w, wv.w, ah);
            }
            ax += __shfl_down(ax, 1, 2); ah += __shfl_down(ah, 1, 2);
            if (sub == 0) {
                lds[L_AX + u] = ax + lds[L_BIH0 + u];
                lds[L_AH + u] = ah + lds[L_BHH0 + u];
            }
        } else if (s == 14) {
            // out base term over weighted (512): threads 192..255 (idle in dots)
            const int f = (tid - 192) >> 3, sub2 = tid & 7;
            float acc = 0.f;
            const float* ow = &outW[f * 1032 + 512 + sub2 * 64];
#pragma unroll 8
            for (int p2 = 0; p2 < 32; ++p2) {
                U32H u; u.u = ldsU[L_HX + 4 + sub2 * 32 + p2];
                acc += ow[2 * p2] * (float)u.h.x + ow[2 * p2 + 1] * (float)u.h.y;
            }
            acc += __shfl_down(acc, 4, 8); acc += __shfl_down(acc, 2, 8); acc += __shfl_down(acc, 1, 8);
            if (sub2 == 0) {
#pragma unroll
                for (int ff = 0; ff < 8; ++ff)
                    acc += outW[f * 1032 + 1024 + ff] * lds[L_XINL + ff];
                cstore(&outBs[par * 128 + b * 8 + f], acc + outBias[f]);
            }
        }
        __syncthreads();
        if (tid < 32) {
            const int r = tid;
            const float rg = fsig(lds[L_AX + r] + lds[L_AH + r]);
            const float z = fsig(lds[L_AX + 32 + r] + lds[L_AH + 32 + r]);
            const float n = ftanhf(lds[L_AX + 64 + r] + rg * lds[L_AH + 64 + r]);
            U32H u; u.u = ldsU[L_H0 + s * 16 + (r >> 1)];
            const float hold = (r & 1) ? (float)u.h.y : (float)u.h.x;
            lds[L_HS + r] = (1.f - z) * n + z * hold;
        }
        __syncthreads();
        if (tid < 16) {
            __hip_atomic_store(&h0cU[(par ^ 1) * 4096 + b * 256 + s * 16 + tid],
                               packh2(lds[L_HS + 2 * tid], lds[L_HS + 2 * tid + 1]),
                               __ATOMIC_RELAXED, __HIP_MEMORY_SCOPE_SYSTEM);
        }
        bar_sync(gcnt, 16u * (++gb));

        // ---- E: GRU1 rows [s*32,+32) + outP partial + accumulator re-zero ----
        ldsU[L_HX + tid] = ucload(&h0cU[(par ^ 1) * 4096 + b * 256 + tid]);  // h0new
        __syncthreads();
        if (tid < 192) {
            const int u = tid >> 1, sub = tid & 1;
            const int gh = u >> 5, r = u & 31;
            const int grow = gh * 512 + s * 32 + r;
            const uint4* wx = (const uint4*)&wih1U[grow * 256 + sub * 128];
            const uint4* xp = (const uint4*)&ldsU[L_HX + sub * 128];
            float ax = 0.f;
#pragma unroll 8
            for (int k4 = 0; k4 < 32; ++k4) {
                const uint4 xv = xp[k4], wv = wx[k4];
                ax = dot2(xv.x, wv.x, ax); ax = dot2(xv.y, wv.y, ax);
                ax = dot2(xv.z, wv.z, ax); ax = dot2(xv.w, wv.w, ax);
            }
            const uint4* wh = (const uint4*)&whh1U[grow * 256 + sub * 128];
            const uint4* hp = (const uint4*)&ldsU[L_H1 + sub * 128];
            float ah = 0.f;
#pragma unroll 8
            for (int k4 = 0; k4 < 32; ++k4) {
                const uint4 hv = hp[k4], wv = wh[k4];
                ah = dot2(hv.x, wv.x, ah); ah = dot2(hv.y, wv.y, ah);
                ah = dot2(hv.z, wv.z, ah); ah = dot2(hv.w, wv.w, ah);
            }
            ax += __shfl_down(ax, 1, 2); ah += __shfl_down(ah, 1, 2);
            if (sub == 0) {
                lds[L_AX + u] = ax + lds[L_BIH1 + u];
                lds[L_AH + u] = ah + lds[L_BHH1 + u];
            }
        }
        __syncthreads();
        if (tid < 32) {
            const int r = tid;
            const float rg = fsig(lds[L_AX + r] + lds[L_AH + r]);
            const float z = fsig(lds[L_AX + 32 + r] + lds[L_AH + 32 + r]);
            const float n = ftanhf(lds[L_AX + 64 + r] + rg * lds[L_AH + 64 + r]);
            U32H u; u.u = ldsU[L_H1 + s * 16 + (r >> 1)];
            const float hold = (r & 1) ? (float)u.h.y : (float)u.h.x;
            lds[L_HS + r] = (1.f - z) * n + z * hold;
        }
        __syncthreads();
        if (tid < 16) {
            __hip_atomic_store(&h1cU[(par ^ 1) * 4096 + b * 256 + s * 16 + tid],
                               packh2(lds[L_HS + 2 * tid], lds[L_HS + 2 * tid + 1]),
                               __ATOMIC_RELAXED, __HIP_MEMORY_SCOPE_SYSTEM);
        }
        if (tid < 64) {
            const int f = tid >> 3, sub = tid & 7;
            float acc = 0.f;
#pragma unroll
            for (int k = 0; k < 4; ++k)
                acc += lds[L_OOW + f * 32 + sub * 4 + k] * lds[L_HS + sub * 4 + k];
            acc += __shfl_down(acc, 4, 8); acc += __shfl_down(acc, 2, 8); acc += __shfl_down(acc, 1, 8);
            if (sub == 0) cstore(&outP[(b * 16 + s) * 8 + f], acc);
        }
        if (s == 0) {
            cstore(&weiA[par * 8192 + b * 512 + tid], 0.f);
            cstore(&weiA[par * 8192 + b * 512 + 256 + tid], 0.f);
            if (tid == 0) cstore(&lacc[par * 16 + b], 0.f);
        }
        bar_sync(gcnt, 16u * (++gb));
    }

    // ---- epilogue: finalize out[31] (par(31) = 1) ----
    if (s == 15 && tid < 64) {
        const int f = tid >> 3, sub = tid & 7;
        float acc = cload(&outP[(b * 16 + sub * 2) * 8 + f]) +
                    cload(&outP[(b * 16 + sub * 2 + 1) * 8 + f]);
        acc += __shfl_down(acc, 4, 8); acc += __shfl_down(acc, 2, 8); acc += __shfl_down(acc, 1, 8);
        if (sub == 0) {
            acc += cload(&outBs[1 * 128 + b * 8 + f]);
            out[b * 256 + 31 * 8 + f] = fmaxf(acc, 0.f);
        }
    }
}

extern "C" void kernel_launch(void* const* d_in, const int* in_sizes, int n_in,
                              void* d_out, int out_size, void* d_ws, size_t ws_size,
                              hipStream_t stream) {
    (void)in_sizes; (void)n_in; (void)out_size; (void)ws_size;
    hipMemsetAsync(d_ws, 0, 4096, stream);  // zero barrier counters
    decoder_kernel<<<NBLK, NTHR, 0, stream>>>(
        (const float*)d_in[0], (const float*)d_in[1], (const float*)d_in[2],
        (const float*)d_in[3], (const float*)d_in[4], (const float*)d_in[5],
        (const float*)d_in[6], (const float*)d_in[7], (const float*)d_in[8],
        (const float*)d_in[9], (const float*)d_in[10], (const float*)d_in[11],
        (const float*)d_in[12], (const float*)d_in[13], (const float*)d_in[14],
        (const float*)d_in[15], (float*)d_out, (float*)d_ws);
}

// Round 4
// 896.017 us; speedup vs baseline: 1.3222x; 1.3003x over previous
//
#include <hip/hip_runtime.h>

// DecoderWithAttention: B=16, T=32, F=8, S_ENC=256, H=512, L=2.
// R10: zero-RMW main loop with tag-embedded signaling (theory: far-atomic
// RMW processing at the coherence point, shared by R7/R8/R9, is the cost).
//  - 16 groups x 16 blocks (bid = b*16 + s), compute layout as R9.
//  - 4 comm points/step, all: payload cstores -> __syncthreads (drains vmcnt)
//    -> one-lane tag cstore (tag value = t+1) -> all-lane poll of 16 tags ->
//    acquire fence -> payload cloads. No atomicAdd, no fetch_add counters.
//  - weiA atomic reduction -> per-slice f32 wpart stores + consumer sum.
//  - out/x_in computed redundantly by every block (s==0 writes out);
//    kills outP/outBs/xinC comm entirely.
//  - Single-buffered comm slots (write of phase k at t+1 is gated by a poll
//    that proves all peers consumed phase k at t).
//  - enc f16 copy dropped (raw f32 enc reads, L2-resident per-slice).

namespace {
constexpr int NBLK = 256, NTHR = 256;

// ws u32 tag layout (zeroed by 32KB memset): tag[(b*16+s)*32 + phase],
// phase 0..3 (128B stride per producer). Prologue grid counter at u32 8180.

// ws float offsets.
constexpr int OFF_AEH   = 8192;                   // [512][256] u32 attn_W[:,512:]
constexpr int OFF_WHID  = OFF_AEH + 131072;       // [512][256] u32 attn_W[:,:512]
constexpr int OFF_WIH0  = OFF_WHID + 131072;      // [1536][260] u32
constexpr int OFF_WHH0  = OFF_WIH0 + 399360;      // [1536][256] u32
constexpr int OFF_WIH1  = OFF_WHH0 + 393216;      // [1536][256] u32
constexpr int OFF_WHH1  = OFF_WIH1 + 393216;      // [1536][256] u32
constexpr int OFF_ENCP  = OFF_WHH1 + 393216;      // [4096][256] u32 enc_proj f16
constexpr int OFF_H0C   = OFF_ENCP + 1048576;     // [16][256] u32 initial h0
constexpr int OFF_H1C   = OFF_H0C + 4096;         // [16][256] u32 initial h1
constexpr int OFF_HIDPS = OFF_H1C + 4096;         // [256][32] f32 hidP slices
constexpr int OFF_WPART = OFF_HIDPS + 8192;       // [256][528] f32 (512 wp + L)
constexpr int OFF_H0S   = OFF_WPART + 135168;     // [256][16] u32 h0new slices
constexpr int OFF_H1S   = OFF_H0S + 4096;         // [256][16] u32 h1new slices
// end = 3,057,664 floats (12.2 MB)

// LDS float/u32 offsets. P2 prologue staging uses [0..8192).
constexpr int L_H1   = 0;      // [256] u32 h1(t) f16x2 full
constexpr int L_H0   = 256;    // [256] u32 h0(t) f16x2 full
constexpr int L_HIDP = 512;    // [512] f32
constexpr int L_ES   = 1024;   // [16]
constexpr int L_HX   = 1040;   // [264] u32: xin(4) | weighted(256) | pad(4)
constexpr int L_AX   = 1304;   // [96]
constexpr int L_AH   = 1400;   // [96]
constexpr int L_BIH0 = 1496, L_BHH0 = 1592, L_BIH1 = 1688, L_BHH1 = 1784;  // [96]
constexpr int L_VW   = 1880;   // [512]
constexpr int L_XINL = 2392;   // [8]
constexpr int LDS_FLOATS = 8192;
}  // namespace

typedef _Float16 h2 __attribute__((ext_vector_type(2)));
union U32H { unsigned u; h2 h; };

__device__ __forceinline__ float dot2(unsigned a, unsigned b, float acc) {
    U32H ua, ub; ua.u = a; ub.u = b;
#if __has_builtin(__builtin_amdgcn_fdot2)
    return __builtin_amdgcn_fdot2(ua.h, ub.h, acc, false);
#else
    return acc + (float)ua.h.x * (float)ub.h.x + (float)ua.h.y * (float)ub.h.y;
#endif
}
__device__ __forceinline__ unsigned packh2(float a, float b) {
    U32H u; u.h = h2{(_Float16)a, (_Float16)b}; return u.u;
}
__device__ __forceinline__ float fsig(float x) { return 1.0f / (1.0f + __expf(-x)); }
__device__ __forceinline__ float ftanhf(float x) {
    float e = __expf(2.0f * x);
    return 1.0f - 2.0f / (e + 1.0f);
}
// Uncached per-access comm ops (sc0 sc1 -> coherence point).
__device__ __forceinline__ float cload(const float* p) {
    return __hip_atomic_load(p, __ATOMIC_RELAXED, __HIP_MEMORY_SCOPE_SYSTEM);
}
__device__ __forceinline__ void cstore(float* p, float v) {
    __hip_atomic_store(p, v, __ATOMIC_RELAXED, __HIP_MEMORY_SCOPE_SYSTEM);
}
__device__ __forceinline__ unsigned ucload(const unsigned* p) {
    return __hip_atomic_load(p, __ATOMIC_RELAXED, __HIP_MEMORY_SCOPE_SYSTEM);
}
__device__ __forceinline__ void ucstore(unsigned* p, unsigned v) {
    __hip_atomic_store(p, v, __ATOMIC_RELAXED, __HIP_MEMORY_SCOPE_SYSTEM);
}

// Prologue barrier: one agent-scope wbl2 (release) / inv (acquire) per block.
__device__ __forceinline__ void bar_sync_flush(unsigned* cnt, unsigned target) {
    __syncthreads();
    if (threadIdx.x == 0) {
        __builtin_amdgcn_fence(__ATOMIC_RELEASE, "agent");
        __hip_atomic_fetch_add(cnt, 1u, __ATOMIC_RELAXED, __HIP_MEMORY_SCOPE_SYSTEM);
        while (__hip_atomic_load(cnt, __ATOMIC_RELAXED, __HIP_MEMORY_SCOPE_SYSTEM) < target)
            __builtin_amdgcn_s_sleep(8);
        __builtin_amdgcn_fence(__ATOMIC_ACQUIRE, "agent");
    }
    __syncthreads();
}

__global__ __launch_bounds__(NTHR) void decoder_kernel(
    const float* __restrict__ target, const float* __restrict__ hidden0,
    const float* __restrict__ enc, const float* __restrict__ attn_W,
    const float* __restrict__ attn_b, const float* __restrict__ v_w,
    const float* __restrict__ Wih0, const float* __restrict__ Whh0,
    const float* __restrict__ bih0, const float* __restrict__ bhh0,
    const float* __restrict__ Wih1, const float* __restrict__ Whh1,
    const float* __restrict__ bih1, const float* __restrict__ bhh1,
    const float* __restrict__ outW, const float* __restrict__ outBias,
    float* __restrict__ out, float* __restrict__ ws) {
    const int tid = threadIdx.x, bid = blockIdx.x;
    const int b = bid >> 4, s = bid & 15;   // group (batch) / slice
    unsigned* tags = (unsigned*)ws;
    unsigned* gridCnt = (unsigned*)ws + 8180;

    unsigned* aehU  = (unsigned*)(ws + OFF_AEH);
    unsigned* whidU = (unsigned*)(ws + OFF_WHID);
    unsigned* wih0U = (unsigned*)(ws + OFF_WIH0);
    unsigned* whh0U = (unsigned*)(ws + OFF_WHH0);
    unsigned* wih1U = (unsigned*)(ws + OFF_WIH1);
    unsigned* whh1U = (unsigned*)(ws + OFF_WHH1);
    unsigned* encpU = (unsigned*)(ws + OFF_ENCP);
    unsigned* h0cU = (unsigned*)(ws + OFF_H0C);
    unsigned* h1cU = (unsigned*)(ws + OFF_H1C);
    float* hidPS = ws + OFF_HIDPS;
    float* wpart = ws + OFF_WPART;
    unsigned* h0S = (unsigned*)(ws + OFF_H0S);
    unsigned* h1S = (unsigned*)(ws + OFF_H1S);

    __shared__ __align__(16) float lds[LDS_FLOATS];
    unsigned* ldsU = (unsigned*)lds;
    const int gtid = bid * NTHR + tid;

    // ===================== P1: f16 pack + initial state (plain stores) ========
    for (int i = gtid; i < 131072; i += NBLK * NTHR) {
        const int jr = i >> 8, p = i & 255;
        aehU[i]  = packh2(attn_W[jr * 1024 + 512 + 2 * p], attn_W[jr * 1024 + 513 + 2 * p]);
        whidU[i] = packh2(attn_W[jr * 1024 + 2 * p], attn_W[jr * 1024 + 1 + 2 * p]);
    }
    for (int i = gtid; i < 399360; i += NBLK * NTHR)
        wih0U[i] = packh2(Wih0[2 * i], Wih0[2 * i + 1]);
    for (int i = gtid; i < 393216; i += NBLK * NTHR) {
        whh0U[i] = packh2(Whh0[2 * i], Whh0[2 * i + 1]);
        wih1U[i] = packh2(Wih1[2 * i], Wih1[2 * i + 1]);
        whh1U[i] = packh2(Whh1[2 * i], Whh1[2 * i + 1]);
    }
    if (gtid < 4096) {
        const int bb = gtid >> 8, p = gtid & 255;
        h0cU[gtid] = packh2(hidden0[bb * 512 + 2 * p], hidden0[bb * 512 + 2 * p + 1]);
        h1cU[gtid] = packh2(hidden0[8192 + bb * 512 + 2 * p], hidden0[8192 + bb * 512 + 2 * p + 1]);
    }
    bar_sync_flush(gridCnt, NBLK);  // one wbl2/inv per block

    // ===================== P2: enc_proj for own (b, 16 s), raw f32 enc ========
    {
        for (int i = 0; i < 32; ++i) {
            const int idx = tid + i * 256;
            lds[idx] = enc[(b * 256 + s * 16) * 512 + idx];  // 16 s x 512
        }
        __syncthreads();
        float a0[16], a1[16];
        const float bb0 = attn_b[2 * tid], bb1 = attn_b[2 * tid + 1];
#pragma unroll
        for (int sl = 0; sl < 16; ++sl) { a0[sl] = bb0; a1[sl] = bb1; }
        const unsigned* w0 = &aehU[(2 * tid) * 256];
        const unsigned* w1 = &aehU[(2 * tid + 1) * 256];
        for (int p = 0; p < 256; ++p) {
            const unsigned ww0 = w0[p], ww1 = w1[p];
#pragma unroll
            for (int sl = 0; sl < 16; ++sl) {
                const unsigned epk = packh2(lds[sl * 512 + 2 * p], lds[sl * 512 + 2 * p + 1]);
                a0[sl] = dot2(epk, ww0, a0[sl]);
                a1[sl] = dot2(epk, ww1, a1[sl]);
            }
        }
        for (int sl = 0; sl < 16; ++sl)  // self-read only (plain, same-XCD L2)
            encpU[(b * 256 + s * 16 + sl) * 256 + tid] = packh2(a0[sl], a1[sl]);
        __syncthreads();
    }

    // ===================== P3: pin biases + v_w in LDS ========================
    if (tid < 96) {
        const int grow = (tid >> 5) * 512 + s * 32 + (tid & 31);
        lds[L_BIH0 + tid] = bih0[grow]; lds[L_BHH0 + tid] = bhh0[grow];
        lds[L_BIH1 + tid] = bih1[grow]; lds[L_BHH1 + tid] = bhh1[grow];
    }
    lds[L_VW + tid] = v_w[tid];
    lds[L_VW + 256 + tid] = v_w[256 + tid];
    __syncthreads();

    // initial state (t=0): h0/h1 full + x_in from target
    ldsU[L_H1 + tid] = ucload(&h1cU[b * 256 + tid]);
    ldsU[L_H0 + tid] = ucload(&h0cU[b * 256 + tid]);
    if (tid < 8) lds[L_XINL + tid] = target[b * 256 + tid];
    __syncthreads();

    // ===================== main recurrence (group-local, tag-polled) ==========
    for (int t = 0; t < 32; ++t) {
        const unsigned tgt = (unsigned)(t + 1);

        // ---- phase 0: hidP own rows [s*32,+32) ----
        {
            const int r = tid >> 3, sub = tid & 7;
            const uint4* wrow = (const uint4*)&whidU[(s * 32 + r) * 256 + sub * 32];
            const uint4* h1p = (const uint4*)&ldsU[L_H1 + sub * 32];
            float acc = 0.f;
#pragma unroll
            for (int k4 = 0; k4 < 8; ++k4) {
                const uint4 hv = h1p[k4], wv = wrow[k4];
                acc = dot2(hv.x, wv.x, acc); acc = dot2(hv.y, wv.y, acc);
                acc = dot2(hv.z, wv.z, acc); acc = dot2(hv.w, wv.w, acc);
            }
            acc += __shfl_down(acc, 4, 8); acc += __shfl_down(acc, 2, 8); acc += __shfl_down(acc, 1, 8);
            if (sub == 0) cstore(&hidPS[(b * 16 + s) * 32 + r], acc);
        }
        __syncthreads();                       // drains payload stores (all waves)
        if (tid == 0) ucstore(&tags[(b * 16 + s) * 32 + 0], tgt);
        {
            const unsigned* tg = &tags[(b * 16 + (tid & 15)) * 32 + 0];
            while (ucload(tg) < tgt) __builtin_amdgcn_s_sleep(1);
        }
        __builtin_amdgcn_fence(__ATOMIC_ACQUIRE, "workgroup");
        lds[L_HIDP + tid] = cload(&hidPS[(b * 16 + (tid >> 5)) * 32 + (tid & 31)]);
        lds[L_HIDP + 256 + tid] = cload(&hidPS[(b * 16 + 8 + (tid >> 5)) * 32 + (tid & 31)]);
        __syncthreads();

        // ---- phase 1: energy own 16 s + exp + wpart (f32 partial, no atomics) -
        {
            const int sloc = tid >> 4, sub = tid & 15;
            const unsigned* ep = &encpU[(b * 256 + s * 16 + sloc) * 256];
            float acc = 0.f;
#pragma unroll 4
            for (int k2 = 0; k2 < 16; ++k2) {
                const int p = k2 * 16 + sub;
                U32H u; u.u = ep[p];
                acc += lds[L_VW + 2 * p] * ftanhf((float)u.h.x + lds[L_HIDP + 2 * p]);
                acc += lds[L_VW + 2 * p + 1] * ftanhf((float)u.h.y + lds[L_HIDP + 2 * p + 1]);
            }
            acc += __shfl_down(acc, 8, 16); acc += __shfl_down(acc, 4, 16);
            acc += __shfl_down(acc, 2, 16); acc += __shfl_down(acc, 1, 16);
            if (sub == 0) lds[L_ES + sloc] = __expf(acc);  // |score|<=~20: fp32-safe
        }
        __syncthreads();
        {
            float wp0 = 0.f, wp1 = 0.f;
            const float2* er = (const float2*)&enc[(b * 256 + s * 16) * 512];
#pragma unroll
            for (int sl = 0; sl < 16; ++sl) {
                const float2 e = er[sl * 256 + tid];
                const float es = lds[L_ES + sl];
                wp0 += es * e.x; wp1 += es * e.y;
            }
            cstore(&wpart[(b * 16 + s) * 528 + 2 * tid], wp0);
            cstore(&wpart[(b * 16 + s) * 528 + 2 * tid + 1], wp1);
            if (tid == 0) {
                float l = 0.f;
#pragma unroll
                for (int i = 0; i < 16; ++i) l += lds[L_ES + i];
                cstore(&wpart[(b * 16 + s) * 528 + 512], l);
            }
        }
        __syncthreads();
        if (tid == 0) ucstore(&tags[(b * 16 + s) * 32 + 1], tgt);
        {
            const unsigned* tg = &tags[(b * 16 + (tid & 15)) * 32 + 1];
            while (ucload(tg) < tgt) __builtin_amdgcn_s_sleep(1);
        }
        __builtin_amdgcn_fence(__ATOMIC_ACQUIRE, "workgroup");
        {
            float w0 = 0.f, w1 = 0.f;
#pragma unroll
            for (int sp = 0; sp < 16; ++sp) {
                w0 += cload(&wpart[(b * 16 + sp) * 528 + 2 * tid]);
                w1 += cload(&wpart[(b * 16 + sp) * 528 + 2 * tid + 1]);
            }
            if (tid < 16) lds[L_ES + tid] = cload(&wpart[(b * 16 + tid) * 528 + 512]);
            __syncthreads();
            float L = 0.f;
#pragma unroll
            for (int i = 0; i < 16; ++i) L += lds[L_ES + i];
            const float inv = 1.f / L;
            ldsU[L_HX + 4 + tid] = packh2(w0 * inv, w1 * inv);
            if (tid < 4) {
                ldsU[L_HX + tid] = packh2(lds[L_XINL + 2 * tid], lds[L_XINL + 2 * tid + 1]);
                ldsU[L_HX + 260 + tid] = 0u;
            }
        }
        __syncthreads();

        // ---- phase 2: GRU0 gate rows [s*32,+32) -> h0new slice ----
        if (tid < 192) {
            const int u = tid >> 1, sub = tid & 1;
            const int gh = u >> 5, r = u & 31;
            const int grow = gh * 512 + s * 32 + r;
            const uint4* wx = (const uint4*)&wih0U[grow * 260 + sub * 132];
            const uint4* xp = (const uint4*)&ldsU[L_HX + sub * 132];
            float ax = 0.f;
#pragma unroll 11
            for (int k4 = 0; k4 < 33; ++k4) {
                const uint4 xv = xp[k4], wv = wx[k4];
                ax = dot2(xv.x, wv.x, ax); ax = dot2(xv.y, wv.y, ax);
                ax = dot2(xv.z, wv.z, ax); ax = dot2(xv.w, wv.w, ax);
            }
            const uint4* wh = (const uint4*)&whh0U[grow * 256 + sub * 128];
            const uint4* hp = (const uint4*)&ldsU[L_H0 + sub * 128];
            float ah = 0.f;
#pragma unroll 8
            for (int k4 = 0; k4 < 32; ++k4) {
                const uint4 hv = hp[k4], wv = wh[k4];
                ah = dot2(hv.x, wv.x, ah); ah = dot2(hv.y, wv.y, ah);
                ah = dot2(hv.z, wv.z, ah); ah = dot2(hv.w, wv.w, ah);
            }
            ax += __shfl_down(ax, 1, 2); ah += __shfl_down(ah, 1, 2);
            if (sub == 0) {
                lds[L_AX + u] = ax + lds[L_BIH0 + u];
                lds[L_AH + u] = ah + lds[L_BHH0 + u];
            }
        }
        __syncthreads();
        if (tid < 32) {
            const int r = tid;
            const float rg = fsig(lds[L_AX + r] + lds[L_AH + r]);
            const float z = fsig(lds[L_AX + 32 + r] + lds[L_AH + 32 + r]);
            const float n = ftanhf(lds[L_AX + 64 + r] + rg * lds[L_AH + 64 + r]);
            U32H u; u.u = ldsU[L_H0 + s * 16 + (r >> 1)];
            const float hold = (r & 1) ? (float)u.h.y : (float)u.h.x;
            const float hs = (1.f - z) * n + z * hold;
            const float hsn = __shfl_down(hs, 1, 2);
            if ((r & 1) == 0)
                ucstore(&h0S[(b * 16 + s) * 16 + (r >> 1)], packh2(hs, hsn));
        }
        __syncthreads();
        if (tid == 0) ucstore(&tags[(b * 16 + s) * 32 + 2], tgt);
        {
            const unsigned* tg = &tags[(b * 16 + (tid & 15)) * 32 + 2];
            while (ucload(tg) < tgt) __builtin_amdgcn_s_sleep(1);
        }
        __builtin_amdgcn_fence(__ATOMIC_ACQUIRE, "workgroup");
        ldsU[L_H0 + tid] = ucload(&h0S[(b * 16 + (tid >> 4)) * 16 + (tid & 15)]);
        __syncthreads();

        // ---- phase 3: GRU1 gate rows [s*32,+32) -> h1new slice ----
        if (tid < 192) {
            const int u = tid >> 1, sub = tid & 1;
            const int gh = u >> 5, r = u & 31;
            const int grow = gh * 512 + s * 32 + r;
            const uint4* wx = (const uint4*)&wih1U[grow * 256 + sub * 128];
            const uint4* xp = (const uint4*)&ldsU[L_H0 + sub * 128];
            float ax = 0.f;
#pragma unroll 8
            for (int k4 = 0; k4 < 32; ++k4) {
                const uint4 xv = xp[k4], wv = wx[k4];
                ax = dot2(xv.x, wv.x, ax); ax = dot2(xv.y, wv.y, ax);
                ax = dot2(xv.z, wv.z, ax); ax = dot2(xv.w, wv.w, ax);
            }
            const uint4* wh = (const uint4*)&whh1U[grow * 256 + sub * 128];
            const uint4* hp = (const uint4*)&ldsU[L_H1 + sub * 128];
            float ah = 0.f;
#pragma unroll 8
            for (int k4 = 0; k4 < 32; ++k4) {
                const uint4 hv = hp[k4], wv = wh[k4];
                ah = dot2(hv.x, wv.x, ah); ah = dot2(hv.y, wv.y, ah);
                ah = dot2(hv.z, wv.z, ah); ah = dot2(hv.w, wv.w, ah);
            }
            ax += __shfl_down(ax, 1, 2); ah += __shfl_down(ah, 1, 2);
            if (sub == 0) {
                lds[L_AX + u] = ax + lds[L_BIH1 + u];
                lds[L_AH + u] = ah + lds[L_BHH1 + u];
            }
        }
        __syncthreads();
        if (tid < 32) {
            const int r = tid;
            const float rg = fsig(lds[L_AX + r] + lds[L_AH + r]);
            const float z = fsig(lds[L_AX + 32 + r] + lds[L_AH + 32 + r]);
            const float n = ftanhf(lds[L_AX + 64 + r] + rg * lds[L_AH + 64 + r]);
            U32H u; u.u = ldsU[L_H1 + s * 16 + (r >> 1)];
            const float hold = (r & 1) ? (float)u.h.y : (float)u.h.x;
            const float hs = (1.f - z) * n + z * hold;
            const float hsn = __shfl_down(hs, 1, 2);
            if ((r & 1) == 0)
                ucstore(&h1S[(b * 16 + s) * 16 + (r >> 1)], packh2(hs, hsn));
        }
        __syncthreads();
        if (tid == 0) ucstore(&tags[(b * 16 + s) * 32 + 3], tgt);
        {
            const unsigned* tg = &tags[(b * 16 + (tid & 15)) * 32 + 3];
            while (ucload(tg) < tgt) __builtin_amdgcn_s_sleep(1);
        }
        __builtin_amdgcn_fence(__ATOMIC_ACQUIRE, "workgroup");
        ldsU[L_H1 + tid] = ucload(&h1S[(b * 16 + (tid >> 4)) * 16 + (tid & 15)]);
        __syncthreads();

        // ---- phase 4 (local): out = relu(outW.[h1new|weighted|xin]+b) --------
        {
            const int f = tid >> 5, l = tid & 31;
            const float* ow = &outW[f * 1032];
            float acc = 0.f;
#pragma unroll
            for (int i = 0; i < 8; ++i) {
                const int k2 = i * 32 + l;
                U32H u; u.u = ldsU[L_H1 + k2];
                acc += ow[2 * k2] * (float)u.h.x + ow[2 * k2 + 1] * (float)u.h.y;
            }
#pragma unroll
            for (int i = 0; i < 8; ++i) {
                const int k2 = i * 32 + l;
                U32H u; u.u = ldsU[L_HX + 4 + k2];
                acc += ow[512 + 2 * k2] * (float)u.h.x + ow[512 + 2 * k2 + 1] * (float)u.h.y;
            }
            if (l < 8) acc += ow[1024 + l] * lds[L_XINL + l];
            acc += __shfl_down(acc, 16, 32); acc += __shfl_down(acc, 8, 32);
            acc += __shfl_down(acc, 4, 32); acc += __shfl_down(acc, 2, 32);
            acc += __shfl_down(acc, 1, 32);
            if (l == 0) {
                const float o = fmaxf(acc + outBias[f], 0.f);
                lds[L_ES + f] = o;
                if (s == 0) out[b * 256 + t * 8 + f] = o;
            }
        }
        __syncthreads();
        if (tid < 8) lds[L_XINL + tid] = lds[L_ES + tid];
        __syncthreads();
    }
}

extern "C" void kernel_launch(void* const* d_in, const int* in_sizes, int n_in,
                              void* d_out, int out_size, void* d_ws, size_t ws_size,
                              hipStream_t stream) {
    (void)in_sizes; (void)n_in; (void)out_size; (void)ws_size;
    hipMemsetAsync(d_ws, 0, 32768, stream);  // zero tag region + grid counter
    decoder_kernel<<<NBLK, NTHR, 0, stream>>>(
        (const float*)d_in[0], (const float*)d_in[1], (const float*)d_in[2],
        (const float*)d_in[3], (const float*)d_in[4], (const float*)d_in[5],
        (const float*)d_in[6], (const float*)d_in[7], (const float*)d_in[8],
        (const float*)d_in[9], (const float*)d_in[10], (const float*)d_in[11],
        (const float*)d_in[12], (const float*)d_in[13], (const float*)d_in[14],
        (const float*)d_in[15], (float*)d_out, (float*)d_ws);
}